// Round 1
// baseline (5850.549 us; speedup 1.0000x reference)
//
#include <hip/hip_runtime.h>
#include <hip/hip_bf16.h>
#include <math.h>

#define SEQ 1024
#define HDIM 1024
#define NHEAD 16
#define HEADD 64
#define LDIM 256
#define RDIM 64
#define DFF 2048
#define NEXP 8
#define ROWS 4096  // B*S

// ---------------- LayerNorm ----------------
__global__ __launch_bounds__(256) void ln_kernel(const float* __restrict__ x,
                                                 const float* __restrict__ g,
                                                 const float* __restrict__ b,
                                                 float* __restrict__ out) {
    int row = blockIdx.x;
    int tid = threadIdx.x;
    __shared__ float red[256];
    __shared__ float red2[256];
    const float* xr = x + (size_t)row * HDIM;
    float s = 0.f, s2 = 0.f;
    for (int j = tid; j < HDIM; j += 256) { float v = xr[j]; s += v; s2 += v * v; }
    red[tid] = s; red2[tid] = s2; __syncthreads();
    for (int o = 128; o > 0; o >>= 1) {
        if (tid < o) { red[tid] += red[tid + o]; red2[tid] += red2[tid + o]; }
        __syncthreads();
    }
    float mean = red[0] * (1.f / HDIM);
    float var = red2[0] * (1.f / HDIM) - mean * mean;
    float inv = rsqrtf(var + 1e-5f);
    for (int j = tid; j < HDIM; j += 256) {
        out[(size_t)row * HDIM + j] = (xr[j] - mean) * inv * g[j] + b[j];
    }
}

// ---------------- Generic tiled GEMM: C = A@B (+R) ----------------
// grid: (N/64, M/64), block 256. M,N multiples of 64; K multiple of 16.
__global__ __launch_bounds__(256) void gemm_kernel(const float* __restrict__ A,
                                                   const float* __restrict__ B,
                                                   float* __restrict__ C,
                                                   const float* __restrict__ R,
                                                   int M, int N, int K) {
    __shared__ float As[16][65];
    __shared__ float Bs[16][64];
    int tid = threadIdx.x;
    int tx = tid & 15, ty = tid >> 4;
    int m0 = blockIdx.y * 64, n0 = blockIdx.x * 64;
    float acc[4][4] = {};
    for (int k0 = 0; k0 < K; k0 += 16) {
        for (int i = 0; i < 4; i++) {
            int id = tid + i * 256;
            int m = id >> 4, k = id & 15;
            As[k][m] = A[(size_t)(m0 + m) * K + k0 + k];
        }
        for (int i = 0; i < 4; i++) {
            int id = tid + i * 256;
            int k = id >> 6, n = id & 63;
            Bs[k][n] = B[(size_t)(k0 + k) * N + n0 + n];
        }
        __syncthreads();
        for (int kk = 0; kk < 16; kk++) {
            float a[4], bv[4];
            for (int i = 0; i < 4; i++) a[i] = As[kk][ty * 4 + i];
            for (int j = 0; j < 4; j++) bv[j] = Bs[kk][tx * 4 + j];
            for (int i = 0; i < 4; i++)
                for (int j = 0; j < 4; j++) acc[i][j] += a[i] * bv[j];
        }
        __syncthreads();
    }
    for (int i = 0; i < 4; i++)
        for (int j = 0; j < 4; j++) {
            size_t idx = (size_t)(m0 + ty * 4 + i) * N + n0 + tx * 4 + j;
            float v = acc[i][j];
            if (R) v += R[idx];
            C[idx] = v;
        }
}

// ---------------- RoPE (in place) ----------------
// tensor layout: rows x (heads*64), interleaved even/odd pairs
__global__ void rope_kernel(float* __restrict__ t, int heads, int total) {
    int idx = blockIdx.x * 256 + threadIdx.x;
    if (idx >= total) return;
    int i = idx & 31;
    int h = (idx >> 5) % heads;
    int row = idx / (32 * heads);
    int s = row & (SEQ - 1);
    float freq = expf(-9.210340372f * (float)i / 32.f);  // 10000^{-i/32}
    float fr = (float)s * freq;
    float sn, cs;
    sincosf(fr, &sn, &cs);
    float* p = t + (size_t)row * heads * 64 + h * 64 + 2 * i;
    float xe = p[0], xo = p[1];
    p[0] = xe * cs - xo * sn;
    p[1] = xe * sn + xo * cs;
}

// ---------------- Attention: one block per (q,h,b) ----------------
__global__ __launch_bounds__(256) void attn_kernel(const float* __restrict__ qc,
                                                   const float* __restrict__ qr,
                                                   const float* __restrict__ kvbuf,
                                                   const float* __restrict__ kr,
                                                   float* __restrict__ o) {
    int qpos = blockIdx.x;
    int h = blockIdx.y;
    int b = blockIdx.z;
    int tid = threadIdx.x;
    __shared__ float qs[128];
    __shared__ float sc[SEQ];
    __shared__ float red[256];
    size_t row = (size_t)b * SEQ + qpos;
    if (tid < 64) {
        qs[tid] = qc[row * HDIM + h * 64 + tid];
        qs[64 + tid] = qr[row * HDIM + h * 64 + tid];
    }
    __syncthreads();
    int nk = qpos + 1;
    float lmax = -1e30f;
    for (int k = tid; k < nk; k += 256) {
        const float* kc = kvbuf + ((size_t)b * SEQ + k) * 2048 + h * 64;
        const float* krp = kr + ((size_t)b * SEQ + k) * 64;
        float d = 0.f;
        for (int j = 0; j < 64; j++) d += qs[j] * kc[j];
        for (int j = 0; j < 64; j++) d += qs[64 + j] * krp[j];
        d *= 0.125f;
        sc[k] = d;
        lmax = fmaxf(lmax, d);
    }
    red[tid] = lmax; __syncthreads();
    for (int ofs = 128; ofs > 0; ofs >>= 1) {
        if (tid < ofs) red[tid] = fmaxf(red[tid], red[tid + ofs]);
        __syncthreads();
    }
    float m = red[0];
    __syncthreads();
    float lsum = 0.f;
    for (int k = tid; k < nk; k += 256) { float e = expf(sc[k] - m); sc[k] = e; lsum += e; }
    red[tid] = lsum; __syncthreads();
    for (int ofs = 128; ofs > 0; ofs >>= 1) {
        if (tid < ofs) red[tid] += red[tid + ofs];
        __syncthreads();
    }
    float inv = 1.f / red[0];
    __syncthreads();
    int d = tid & 63, c = tid >> 6;
    float part = 0.f;
    for (int k = c; k < nk; k += 4) {
        part += sc[k] * kvbuf[((size_t)b * SEQ + k) * 2048 + 1024 + h * 64 + d];
    }
    red[tid] = part; __syncthreads();
    if (tid < 64) {
        float v = (red[d] + red[64 + d] + red[128 + d] + red[192 + d]) * inv;
        o[row * HDIM + h * 64 + d] = v;
    }
}

// ---------------- zero small int scratch ----------------
__global__ void init_kernel(int* counts, int* pos) {
    int t = threadIdx.x;
    if (t < NEXP) { counts[t] = 0; pos[t] = 0; }
}

// ---------------- Routing: one wave per row ----------------
__global__ __launch_bounds__(64) void route_kernel(const float* __restrict__ xf,
                                                   const float* __restrict__ cent,
                                                   const float* __restrict__ rbias,
                                                   int* __restrict__ route_i,
                                                   float* __restrict__ route_w,
                                                   int* __restrict__ counts) {
    int row = blockIdx.x;
    int lane = threadIdx.x;
    const float* xr = xf + (size_t)row * HDIM;
    float p[NEXP] = {};
    for (int j = lane; j < HDIM; j += 64) {
        float xv = xr[j];
        for (int e = 0; e < NEXP; e++) p[e] += xv * cent[e * HDIM + j];
    }
    for (int e = 0; e < NEXP; e++) {
        float v = p[e];
        for (int o = 32; o > 0; o >>= 1) v += __shfl_down(v, o);
        p[e] = v;
    }
    if (lane == 0) {
        float biased[NEXP];
        for (int e = 0; e < NEXP; e++) {
            float aff = 1.f / (1.f + expf(-p[e]));
            biased[e] = aff + rbias[e];
        }
        int i0 = 0; float v0 = biased[0];
        for (int e = 1; e < NEXP; e++) if (biased[e] > v0) { v0 = biased[e]; i0 = e; }
        int i1 = -1; float v1 = -1e30f;
        for (int e = 0; e < NEXP; e++) if (e != i0 && biased[e] > v1) { v1 = biased[e]; i1 = e; }
        float e1 = expf(v1 - v0);
        float wsum = 1.f + e1;
        route_i[row * 2] = i0; route_i[row * 2 + 1] = i1;
        route_w[row * 2] = 1.f / wsum; route_w[row * 2 + 1] = e1 / wsum;
        atomicAdd(&counts[i0], 1);
        atomicAdd(&counts[i1], 1);
    }
}

__global__ void offsets_kernel(const int* counts, int* eoff, float* out_counts) {
    int acc = 0;
    for (int e = 0; e < NEXP; e++) { eoff[e] = acc; acc += counts[e]; out_counts[e] = (float)counts[e]; }
    eoff[NEXP] = acc;
}

__global__ void scatter_kernel(const int* route_i, const float* route_w, const int* eoff,
                               int* pos, int* tok_id, float* tok_w) {
    int row = blockIdx.x * 256 + threadIdx.x;
    if (row >= ROWS) return;
    for (int sl = 0; sl < 2; sl++) {
        int e = route_i[row * 2 + sl];
        int p = atomicAdd(&pos[e], 1);
        int dst = eoff[e] + p;
        tok_id[dst] = row;
        tok_w[dst] = route_w[row * 2 + sl];
    }
}

// ---------------- MoE gate/up: hh = silu(X@Wg)*(X@Wu), gathered rows ----------------
// grid: (DFF/64, 128, NEXP)
__global__ __launch_bounds__(256) void moe_gu_kernel(const float* __restrict__ xf,
                                                     const float* __restrict__ Wg,
                                                     const float* __restrict__ Wu,
                                                     const int* __restrict__ counts,
                                                     const int* __restrict__ eoff,
                                                     const int* __restrict__ tok_id,
                                                     float* __restrict__ hh) {
    int e = blockIdx.z;
    int n_e = counts[e];
    int t0 = blockIdx.y * 64;
    if (t0 >= n_e) return;
    int n0 = blockIdx.x * 64;
    const float* Wge = Wg + (size_t)e * HDIM * DFF;
    const float* Wue = Wu + (size_t)e * HDIM * DFF;
    int tid = threadIdx.x;
    int tx = tid & 15, ty = tid >> 4;
    __shared__ float As[16][65];
    __shared__ float Bg[16][64];
    __shared__ float Bu[16][64];
    __shared__ int toks[64];
    if (tid < 64) {
        int idx = t0 + tid;
        toks[tid] = (idx < n_e) ? tok_id[eoff[e] + idx] : 0;
    }
    __syncthreads();
    float accg[4][4] = {}, accu[4][4] = {};
    for (int k0 = 0; k0 < HDIM; k0 += 16) {
        for (int i = 0; i < 4; i++) {
            int id = tid + i * 256;
            int m = id >> 4, k = id & 15;
            As[k][m] = xf[(size_t)toks[m] * HDIM + k0 + k];
        }
        for (int i = 0; i < 4; i++) {
            int id = tid + i * 256;
            int k = id >> 6, n = id & 63;
            Bg[k][n] = Wge[(size_t)(k0 + k) * DFF + n0 + n];
            Bu[k][n] = Wue[(size_t)(k0 + k) * DFF + n0 + n];
        }
        __syncthreads();
        for (int kk = 0; kk < 16; kk++) {
            float a[4], bg[4], bu[4];
            for (int i = 0; i < 4; i++) a[i] = As[kk][ty * 4 + i];
            for (int j = 0; j < 4; j++) { bg[j] = Bg[kk][tx * 4 + j]; bu[j] = Bu[kk][tx * 4 + j]; }
            for (int i = 0; i < 4; i++)
                for (int j = 0; j < 4; j++) { accg[i][j] += a[i] * bg[j]; accu[i][j] += a[i] * bu[j]; }
        }
        __syncthreads();
    }
    for (int i = 0; i < 4; i++) {
        int r = ty * 4 + i;
        if (t0 + r >= n_e) continue;
        size_t slot = (size_t)eoff[e] + t0 + r;
        for (int j = 0; j < 4; j++) {
            float gg = accg[i][j];
            float uu = accu[i][j];
            float sg = gg / (1.f + expf(-gg));
            hh[slot * DFF + n0 + tx * 4 + j] = sg * uu;
        }
    }
}

// ---------------- MoE down: out += w * hh@Wd, scatter atomically ----------------
// grid: (HDIM/64, 128, NEXP)
__global__ __launch_bounds__(256) void moe_down_kernel(const float* __restrict__ hh,
                                                       const float* __restrict__ Wd,
                                                       const int* __restrict__ counts,
                                                       const int* __restrict__ eoff,
                                                       const int* __restrict__ tok_id,
                                                       const float* __restrict__ tok_w,
                                                       float* __restrict__ out) {
    int e = blockIdx.z;
    int n_e = counts[e];
    int t0 = blockIdx.y * 64;
    if (t0 >= n_e) return;
    int n0 = blockIdx.x * 64;
    const float* Wde = Wd + (size_t)e * DFF * HDIM;
    const float* Ae = hh + (size_t)eoff[e] * DFF;
    int tid = threadIdx.x;
    int tx = tid & 15, ty = tid >> 4;
    __shared__ float As[16][65];
    __shared__ float Bs[16][64];
    float acc[4][4] = {};
    for (int k0 = 0; k0 < DFF; k0 += 16) {
        for (int i = 0; i < 4; i++) {
            int id = tid + i * 256;
            int m = id >> 4, k = id & 15;
            As[k][m] = Ae[(size_t)(t0 + m) * DFF + k0 + k];
        }
        for (int i = 0; i < 4; i++) {
            int id = tid + i * 256;
            int k = id >> 6, n = id & 63;
            Bs[k][n] = Wde[(size_t)(k0 + k) * HDIM + n0 + n];
        }
        __syncthreads();
        for (int kk = 0; kk < 16; kk++) {
            float a[4], bv[4];
            for (int i = 0; i < 4; i++) a[i] = As[kk][ty * 4 + i];
            for (int j = 0; j < 4; j++) bv[j] = Bs[kk][tx * 4 + j];
            for (int i = 0; i < 4; i++)
                for (int j = 0; j < 4; j++) acc[i][j] += a[i] * bv[j];
        }
        __syncthreads();
    }
    for (int i = 0; i < 4; i++) {
        int r = t0 + ty * 4 + i;
        if (r >= n_e) continue;
        int slot = eoff[e] + r;
        int tok = tok_id[slot];
        float w = tok_w[slot];
        for (int j = 0; j < 4; j++) {
            atomicAdd(&out[(size_t)tok * HDIM + n0 + tx * 4 + j], w * acc[i][j]);
        }
    }
}

extern "C" void kernel_launch(void* const* d_in, const int* in_sizes, int n_in,
                              void* d_out, int out_size, void* d_ws, size_t ws_size,
                              hipStream_t stream) {
    const float* x = (const float*)d_in[0];
    const float* ln1_g = (const float*)d_in[1];
    const float* ln1_b = (const float*)d_in[2];
    const float* W_ckv = (const float*)d_in[3];
    const float* W_kv = (const float*)d_in[4];
    const float* W_cq = (const float*)d_in[5];
    const float* W_q = (const float*)d_in[6];
    const float* W_qr = (const float*)d_in[7];
    const float* W_kr = (const float*)d_in[8];
    const float* W_o = (const float*)d_in[9];
    const float* ln2_g = (const float*)d_in[10];
    const float* ln2_b = (const float*)d_in[11];
    const float* cent = (const float*)d_in[12];
    const float* rbias = (const float*)d_in[13];
    const float* Wg = (const float*)d_in[14];
    const float* Wu = (const float*)d_in[15];
    const float* Wd = (const float*)d_in[16];
    float* out = (float*)d_out;

    float* ws = (float*)d_ws;
    size_t off = 0;
    float* h1 = ws + off;    off += (size_t)ROWS * HDIM;
    float* c_kv = ws + off;  off += (size_t)ROWS * LDIM;
    float* c_q = ws + off;   off += (size_t)ROWS * LDIM;
    float* kv = ws + off;    off += (size_t)ROWS * 2048;
    float* q_c = ws + off;   off += (size_t)ROWS * HDIM;
    float* q_r = ws + off;   off += (size_t)ROWS * HDIM;
    float* k_r = ws + off;   off += (size_t)ROWS * RDIM;
    float* obuf = ws + off;  off += (size_t)ROWS * HDIM;
    float* xf = ws + off;    off += (size_t)ROWS * HDIM;
    float* hh = ws + off;    off += (size_t)(ROWS * 2 + 64) * DFF;
    float* route_w = ws + off; off += ROWS * 2;
    float* tok_w = ws + off;   off += ROWS * 2;
    int* ibuf = (int*)(ws + off);
    int* route_i = ibuf;           // 8192
    int* counts = ibuf + 8192;     // 8
    int* eoff = ibuf + 8200;       // 9
    int* pos = ibuf + 8212;        // 8
    int* tok_id = ibuf + 8224;     // 8192

    // 1. LN1
    ln_kernel<<<ROWS, 256, 0, stream>>>(x, ln1_g, ln1_b, h1);
    // 2. c_kv = h1 @ W_ckv  (4096x1024 @ 1024x256)
    gemm_kernel<<<dim3(LDIM / 64, ROWS / 64), 256, 0, stream>>>(h1, W_ckv, c_kv, nullptr, ROWS, LDIM, HDIM);
    // 3. c_q = h1 @ W_cq
    gemm_kernel<<<dim3(LDIM / 64, ROWS / 64), 256, 0, stream>>>(h1, W_cq, c_q, nullptr, ROWS, LDIM, HDIM);
    // 4. kv = c_kv @ W_kv (4096x256 @ 256x2048)
    gemm_kernel<<<dim3(2048 / 64, ROWS / 64), 256, 0, stream>>>(c_kv, W_kv, kv, nullptr, ROWS, 2048, LDIM);
    // 5. q_c = c_q @ W_q
    gemm_kernel<<<dim3(HDIM / 64, ROWS / 64), 256, 0, stream>>>(c_q, W_q, q_c, nullptr, ROWS, HDIM, LDIM);
    // 6. q_r = c_q @ W_qr
    gemm_kernel<<<dim3(HDIM / 64, ROWS / 64), 256, 0, stream>>>(c_q, W_qr, q_r, nullptr, ROWS, HDIM, LDIM);
    // 7. k_r = c_kv @ W_kr (N=64)
    gemm_kernel<<<dim3(1, ROWS / 64), 256, 0, stream>>>(c_kv, W_kr, k_r, nullptr, ROWS, RDIM, LDIM);
    // 8. RoPE q_r (16 heads), k_r (1 head)
    {
        int total_q = ROWS * NHEAD * 32;
        rope_kernel<<<(total_q + 255) / 256, 256, 0, stream>>>(q_r, NHEAD, total_q);
        int total_k = ROWS * 1 * 32;
        rope_kernel<<<(total_k + 255) / 256, 256, 0, stream>>>(k_r, 1, total_k);
    }
    // 9. attention -> obuf
    attn_kernel<<<dim3(SEQ, NHEAD, 4), 256, 0, stream>>>(q_c, q_r, kv, k_r, obuf);
    // 10. out = obuf @ W_o + x   (residual 1) -> d_out
    gemm_kernel<<<dim3(HDIM / 64, ROWS / 64), 256, 0, stream>>>(obuf, W_o, out, x, ROWS, HDIM, HDIM);
    // 11. LN2 -> xf
    ln_kernel<<<ROWS, 256, 0, stream>>>(out, ln2_g, ln2_b, xf);
    // 12. routing
    init_kernel<<<1, 64, 0, stream>>>(counts, pos);
    route_kernel<<<ROWS, 64, 0, stream>>>(xf, cent, rbias, route_i, route_w, counts);
    offsets_kernel<<<1, 1, 0, stream>>>(counts, eoff, out + (size_t)ROWS * HDIM);
    scatter_kernel<<<ROWS / 256, 256, 0, stream>>>(route_i, route_w, eoff, pos, tok_id, tok_w);
    // 13. MoE gate/up -> hh
    moe_gu_kernel<<<dim3(DFF / 64, 128, NEXP), 256, 0, stream>>>(xf, Wg, Wu, counts, eoff, tok_id, hh);
    // 14. MoE down-proj, atomic accumulate into out (residual 2)
    moe_down_kernel<<<dim3(HDIM / 64, 128, NEXP), 256, 0, stream>>>(hh, Wd, counts, eoff, tok_id, tok_w, out);
}

// Round 3
// 2898.557 us; speedup vs baseline: 2.0184x; 2.0184x over previous
//
#include <hip/hip_runtime.h>
#include <hip/hip_bf16.h>
#include <math.h>

#define SEQ 1024
#define HDIM 1024
#define NHEAD 16
#define HEADD 64
#define LDIM 256
#define RDIM 64
#define DFF 2048
#define NEXP 8
#define ROWS 4096  // B*S

// ---------------- LayerNorm ----------------
__global__ __launch_bounds__(256) void ln_kernel(const float* __restrict__ x,
                                                 const float* __restrict__ g,
                                                 const float* __restrict__ b,
                                                 float* __restrict__ out) {
    int row = blockIdx.x;
    int tid = threadIdx.x;
    __shared__ float red[256];
    __shared__ float red2[256];
    const float* xr = x + (size_t)row * HDIM;
    float s = 0.f, s2 = 0.f;
    for (int j = tid; j < HDIM; j += 256) { float v = xr[j]; s += v; s2 += v * v; }
    red[tid] = s; red2[tid] = s2; __syncthreads();
    for (int o = 128; o > 0; o >>= 1) {
        if (tid < o) { red[tid] += red[tid + o]; red2[tid] += red2[tid + o]; }
        __syncthreads();
    }
    float mean = red[0] * (1.f / HDIM);
    float var = red2[0] * (1.f / HDIM) - mean * mean;
    float inv = rsqrtf(var + 1e-5f);
    for (int j = tid; j < HDIM; j += 256) {
        out[(size_t)row * HDIM + j] = (xr[j] - mean) * inv * g[j] + b[j];
    }
}

// ---------------- Generic tiled GEMM: C = A@B (+R) ----------------
__global__ __launch_bounds__(256) void gemm_kernel(const float* __restrict__ A,
                                                   const float* __restrict__ B,
                                                   float* __restrict__ C,
                                                   const float* __restrict__ R,
                                                   int M, int N, int K) {
    __shared__ float As[16][65];
    __shared__ float Bs[16][64];
    int tid = threadIdx.x;
    int tx = tid & 15, ty = tid >> 4;
    int m0 = blockIdx.y * 64, n0 = blockIdx.x * 64;
    float acc[4][4] = {};
    for (int k0 = 0; k0 < K; k0 += 16) {
        for (int i = 0; i < 4; i++) {
            int id = tid + i * 256;
            int m = id >> 4, k = id & 15;
            As[k][m] = A[(size_t)(m0 + m) * K + k0 + k];
        }
        for (int i = 0; i < 4; i++) {
            int id = tid + i * 256;
            int k = id >> 6, n = id & 63;
            Bs[k][n] = B[(size_t)(k0 + k) * N + n0 + n];
        }
        __syncthreads();
        for (int kk = 0; kk < 16; kk++) {
            float a[4], bv[4];
            for (int i = 0; i < 4; i++) a[i] = As[kk][ty * 4 + i];
            for (int j = 0; j < 4; j++) bv[j] = Bs[kk][tx * 4 + j];
            for (int i = 0; i < 4; i++)
                for (int j = 0; j < 4; j++) acc[i][j] += a[i] * bv[j];
        }
        __syncthreads();
    }
    for (int i = 0; i < 4; i++)
        for (int j = 0; j < 4; j++) {
            size_t idx = (size_t)(m0 + ty * 4 + i) * N + n0 + tx * 4 + j;
            float v = acc[i][j];
            if (R) v += R[idx];
            C[idx] = v;
        }
}

// ---------------- RoPE (in place) ----------------
__global__ void rope_kernel(float* __restrict__ t, int heads, int total) {
    int idx = blockIdx.x * 256 + threadIdx.x;
    if (idx >= total) return;
    int i = idx & 31;
    int h = (idx >> 5) % heads;
    int row = idx / (32 * heads);
    int s = row & (SEQ - 1);
    float freq = expf(-9.210340372f * (float)i / 32.f);  // 10000^{-i/32}
    float fr = (float)s * freq;
    float sn, cs;
    sincosf(fr, &sn, &cs);
    float* p = t + (size_t)row * heads * 64 + h * 64 + 2 * i;
    float xe = p[0], xo = p[1];
    p[0] = xe * cs - xo * sn;
    p[1] = xe * sn + xo * cs;
}

// ---------------- Flash attention (fp32, tiled) ----------------
// grid: (SEQ/64, NHEAD, B), block 256.
__global__ __launch_bounds__(256) void attn_flash_kernel(const float* __restrict__ qc,
                                                         const float* __restrict__ qr,
                                                         const float* __restrict__ kvbuf,
                                                         const float* __restrict__ kr,
                                                         float* __restrict__ o) {
    int qt = blockIdx.x, h = blockIdx.y, b = blockIdx.z;
    int tid = threadIdx.x;
    int tx = tid & 15, ty = tid >> 4;
    __shared__ float SA[64][68];  // rows 0..31: Q-chunk (d-major); rows 32..63: K-chunk; reused as P[64][.]
    __shared__ float Vs[64][68];
    float acc[4][4] = {};
    float mrow[4], lrow[4];
    for (int i = 0; i < 4; i++) { mrow[i] = -1e30f; lrow[i] = 0.f; }
    int q0 = qt * 64;
    size_t brow = (size_t)b * SEQ;

    for (int kt = 0; kt <= qt; ++kt) {
        int k0 = kt * 64;
        float s[4][4] = {};
        // ---- QK^T over 4 d-chunks of 32 ----
        for (int dc = 0; dc < 4; ++dc) {
            int dbase = dc * 32;
            __syncthreads();
            #pragma unroll
            for (int it = 0; it < 8; ++it) {
                int id = tid + it * 256;
                int d = id & 31, r = id >> 5;
                float qv, kval;
                if (dbase < 64) {
                    qv = qc[(brow + q0 + r) * HDIM + h * 64 + dbase + d];
                    kval = kvbuf[(brow + k0 + r) * 2048 + h * 64 + dbase + d];
                } else {
                    qv = qr[(brow + q0 + r) * HDIM + h * 64 + (dbase - 64) + d];
                    kval = kr[(brow + k0 + r) * 64 + (dbase - 64) + d];
                }
                SA[d][r] = qv;        // Q chunk
                SA[32 + d][r] = kval; // K chunk
            }
            __syncthreads();
            #pragma unroll 4
            for (int kk = 0; kk < 32; ++kk) {
                float a0 = SA[kk][ty * 4 + 0];
                float a1 = SA[kk][ty * 4 + 1];
                float a2 = SA[kk][ty * 4 + 2];
                float a3 = SA[kk][ty * 4 + 3];
                float b0 = SA[32 + kk][tx * 4 + 0];
                float b1 = SA[32 + kk][tx * 4 + 1];
                float b2 = SA[32 + kk][tx * 4 + 2];
                float b3 = SA[32 + kk][tx * 4 + 3];
                s[0][0] += a0 * b0; s[0][1] += a0 * b1; s[0][2] += a0 * b2; s[0][3] += a0 * b3;
                s[1][0] += a1 * b0; s[1][1] += a1 * b1; s[1][2] += a1 * b2; s[1][3] += a1 * b3;
                s[2][0] += a2 * b0; s[2][1] += a2 * b1; s[2][2] += a2 * b2; s[2][3] += a2 * b3;
                s[3][0] += a3 * b0; s[3][1] += a3 * b1; s[3][2] += a3 * b2; s[3][3] += a3 * b3;
            }
        }
        // ---- scale + causal mask ----
        #pragma unroll
        for (int i = 0; i < 4; i++)
            #pragma unroll
            for (int j = 0; j < 4; j++) {
                s[i][j] *= 0.125f;
                if (kt == qt && (k0 + tx * 4 + j) > (q0 + ty * 4 + i)) s[i][j] = -1e30f;
            }
        // ---- online softmax (row stats across 16 tx lanes) ----
        float p[4][4];
        #pragma unroll
        for (int i = 0; i < 4; i++) {
            float tmax = fmaxf(fmaxf(s[i][0], s[i][1]), fmaxf(s[i][2], s[i][3]));
            tmax = fmaxf(tmax, __shfl_xor(tmax, 1));
            tmax = fmaxf(tmax, __shfl_xor(tmax, 2));
            tmax = fmaxf(tmax, __shfl_xor(tmax, 4));
            tmax = fmaxf(tmax, __shfl_xor(tmax, 8));
            float mnew = fmaxf(mrow[i], tmax);
            float psum = 0.f;
            #pragma unroll
            for (int j = 0; j < 4; j++) { p[i][j] = expf(s[i][j] - mnew); psum += p[i][j]; }
            psum += __shfl_xor(psum, 1);
            psum += __shfl_xor(psum, 2);
            psum += __shfl_xor(psum, 4);
            psum += __shfl_xor(psum, 8);
            float factor = expf(mrow[i] - mnew);
            lrow[i] = lrow[i] * factor + psum;
            #pragma unroll
            for (int j = 0; j < 4; j++) acc[i][j] *= factor;
            mrow[i] = mnew;
        }
        // ---- stage P into SA (alias) + load V tile ----
        __syncthreads();  // all waves done reading Q/K chunks
        #pragma unroll
        for (int i = 0; i < 4; i++)
            #pragma unroll
            for (int j = 0; j < 4; j++) SA[ty * 4 + i][tx * 4 + j] = p[i][j];
        #pragma unroll
        for (int it = 0; it < 16; ++it) {
            int id = tid + it * 256;
            int d = id & 63, r = id >> 6;
            Vs[r][d] = kvbuf[(brow + k0 + r) * 2048 + 1024 + h * 64 + d];
        }
        __syncthreads();
        // ---- PV ----
        #pragma unroll 4
        for (int kk = 0; kk < 64; ++kk) {
            float v0 = Vs[kk][tx * 4 + 0];
            float v1 = Vs[kk][tx * 4 + 1];
            float v2 = Vs[kk][tx * 4 + 2];
            float v3 = Vs[kk][tx * 4 + 3];
            #pragma unroll
            for (int i = 0; i < 4; i++) {
                float pb = SA[ty * 4 + i][kk];
                acc[i][0] += pb * v0; acc[i][1] += pb * v1; acc[i][2] += pb * v2; acc[i][3] += pb * v3;
            }
        }
    }
    // ---- epilogue ----
    #pragma unroll
    for (int i = 0; i < 4; i++) {
        float inv = 1.f / lrow[i];
        #pragma unroll
        for (int j = 0; j < 4; j++) {
            o[(brow + q0 + ty * 4 + i) * HDIM + h * 64 + tx * 4 + j] = acc[i][j] * inv;
        }
    }
}

// ---------------- zero small int scratch ----------------
__global__ void init_kernel(int* counts, int* pos) {
    int t = threadIdx.x;
    if (t < NEXP) { counts[t] = 0; pos[t] = 0; }
}

// ---------------- Routing: one wave per row ----------------
__global__ __launch_bounds__(64) void route_kernel(const float* __restrict__ xf,
                                                   const float* __restrict__ cent,
                                                   const float* __restrict__ rbias,
                                                   int* __restrict__ route_i,
                                                   float* __restrict__ route_w,
                                                   int* __restrict__ counts) {
    int row = blockIdx.x;
    int lane = threadIdx.x;
    const float* xr = xf + (size_t)row * HDIM;
    float p[NEXP] = {};
    for (int j = lane; j < HDIM; j += 64) {
        float xv = xr[j];
        for (int e = 0; e < NEXP; e++) p[e] += xv * cent[e * HDIM + j];
    }
    for (int e = 0; e < NEXP; e++) {
        float v = p[e];
        for (int o = 32; o > 0; o >>= 1) v += __shfl_down(v, o);
        p[e] = v;
    }
    if (lane == 0) {
        float biased[NEXP];
        for (int e = 0; e < NEXP; e++) {
            float aff = 1.f / (1.f + expf(-p[e]));
            biased[e] = aff + rbias[e];
        }
        int i0 = 0; float v0 = biased[0];
        for (int e = 1; e < NEXP; e++) if (biased[e] > v0) { v0 = biased[e]; i0 = e; }
        int i1 = -1; float v1 = -1e30f;
        for (int e = 0; e < NEXP; e++) if (e != i0 && biased[e] > v1) { v1 = biased[e]; i1 = e; }
        float e1 = expf(v1 - v0);
        float wsum = 1.f + e1;
        route_i[row * 2] = i0; route_i[row * 2 + 1] = i1;
        route_w[row * 2] = 1.f / wsum; route_w[row * 2 + 1] = e1 / wsum;
        atomicAdd(&counts[i0], 1);
        atomicAdd(&counts[i1], 1);
    }
}

__global__ void offsets_kernel(const int* counts, int* eoff, float* out_counts) {
    int acc = 0;
    for (int e = 0; e < NEXP; e++) { eoff[e] = acc; acc += counts[e]; out_counts[e] = (float)counts[e]; }
    eoff[NEXP] = acc;
}

__global__ void scatter_kernel(const int* route_i, const float* route_w, const int* eoff,
                               int* pos, int* tok_id, float* tok_w) {
    int row = blockIdx.x * 256 + threadIdx.x;
    if (row >= ROWS) return;
    for (int sl = 0; sl < 2; sl++) {
        int e = route_i[row * 2 + sl];
        int p = atomicAdd(&pos[e], 1);
        int dst = eoff[e] + p;
        tok_id[dst] = row;
        tok_w[dst] = route_w[row * 2 + sl];
    }
}

// ---------------- MoE gate/up ----------------
__global__ __launch_bounds__(256) void moe_gu_kernel(const float* __restrict__ xf,
                                                     const float* __restrict__ Wg,
                                                     const float* __restrict__ Wu,
                                                     const int* __restrict__ counts,
                                                     const int* __restrict__ eoff,
                                                     const int* __restrict__ tok_id,
                                                     float* __restrict__ hh) {
    int e = blockIdx.z;
    int n_e = counts[e];
    int t0 = blockIdx.y * 64;
    if (t0 >= n_e) return;
    int n0 = blockIdx.x * 64;
    const float* Wge = Wg + (size_t)e * HDIM * DFF;
    const float* Wue = Wu + (size_t)e * HDIM * DFF;
    int tid = threadIdx.x;
    int tx = tid & 15, ty = tid >> 4;
    __shared__ float As[16][65];
    __shared__ float Bg[16][64];
    __shared__ float Bu[16][64];
    __shared__ int toks[64];
    if (tid < 64) {
        int idx = t0 + tid;
        toks[tid] = (idx < n_e) ? tok_id[eoff[e] + idx] : 0;
    }
    __syncthreads();
    float accg[4][4] = {}, accu[4][4] = {};
    for (int k0 = 0; k0 < HDIM; k0 += 16) {
        for (int i = 0; i < 4; i++) {
            int id = tid + i * 256;
            int m = id >> 4, k = id & 15;
            As[k][m] = xf[(size_t)toks[m] * HDIM + k0 + k];
        }
        for (int i = 0; i < 4; i++) {
            int id = tid + i * 256;
            int k = id >> 6, n = id & 63;
            Bg[k][n] = Wge[(size_t)(k0 + k) * DFF + n0 + n];
            Bu[k][n] = Wue[(size_t)(k0 + k) * DFF + n0 + n];
        }
        __syncthreads();
        for (int kk = 0; kk < 16; kk++) {
            float a[4], bg[4], bu[4];
            for (int i = 0; i < 4; i++) a[i] = As[kk][ty * 4 + i];
            for (int j = 0; j < 4; j++) { bg[j] = Bg[kk][tx * 4 + j]; bu[j] = Bu[kk][tx * 4 + j]; }
            for (int i = 0; i < 4; i++)
                for (int j = 0; j < 4; j++) { accg[i][j] += a[i] * bg[j]; accu[i][j] += a[i] * bu[j]; }
        }
        __syncthreads();
    }
    for (int i = 0; i < 4; i++) {
        int r = ty * 4 + i;
        if (t0 + r >= n_e) continue;
        size_t slot = (size_t)eoff[e] + t0 + r;
        for (int j = 0; j < 4; j++) {
            float gg = accg[i][j];
            float uu = accu[i][j];
            float sg = gg / (1.f + expf(-gg));
            hh[slot * DFF + n0 + tx * 4 + j] = sg * uu;
        }
    }
}

// ---------------- MoE down ----------------
__global__ __launch_bounds__(256) void moe_down_kernel(const float* __restrict__ hh,
                                                       const float* __restrict__ Wd,
                                                       const int* __restrict__ counts,
                                                       const int* __restrict__ eoff,
                                                       const int* __restrict__ tok_id,
                                                       const float* __restrict__ tok_w,
                                                       float* __restrict__ out) {
    int e = blockIdx.z;
    int n_e = counts[e];
    int t0 = blockIdx.y * 64;
    if (t0 >= n_e) return;
    int n0 = blockIdx.x * 64;
    const float* Wde = Wd + (size_t)e * DFF * HDIM;
    const float* Ae = hh + (size_t)eoff[e] * DFF;
    int tid = threadIdx.x;
    int tx = tid & 15, ty = tid >> 4;
    __shared__ float As[16][65];
    __shared__ float Bs[16][64];
    float acc[4][4] = {};
    for (int k0 = 0; k0 < DFF; k0 += 16) {
        for (int i = 0; i < 4; i++) {
            int id = tid + i * 256;
            int m = id >> 4, k = id & 15;
            As[k][m] = Ae[(size_t)(t0 + m) * DFF + k0 + k];
        }
        for (int i = 0; i < 4; i++) {
            int id = tid + i * 256;
            int k = id >> 6, n = id & 63;
            Bs[k][n] = Wde[(size_t)(k0 + k) * HDIM + n0 + n];
        }
        __syncthreads();
        for (int kk = 0; kk < 16; kk++) {
            float a[4], bv[4];
            for (int i = 0; i < 4; i++) a[i] = As[kk][ty * 4 + i];
            for (int j = 0; j < 4; j++) bv[j] = Bs[kk][tx * 4 + j];
            for (int i = 0; i < 4; i++)
                for (int j = 0; j < 4; j++) acc[i][j] += a[i] * bv[j];
        }
        __syncthreads();
    }
    for (int i = 0; i < 4; i++) {
        int r = t0 + ty * 4 + i;
        if (r >= n_e) continue;
        int slot = eoff[e] + r;
        int tok = tok_id[slot];
        float w = tok_w[slot];
        for (int j = 0; j < 4; j++) {
            atomicAdd(&out[(size_t)tok * HDIM + n0 + tx * 4 + j], w * acc[i][j]);
        }
    }
}

extern "C" void kernel_launch(void* const* d_in, const int* in_sizes, int n_in,
                              void* d_out, int out_size, void* d_ws, size_t ws_size,
                              hipStream_t stream) {
    const float* x = (const float*)d_in[0];
    const float* ln1_g = (const float*)d_in[1];
    const float* ln1_b = (const float*)d_in[2];
    const float* W_ckv = (const float*)d_in[3];
    const float* W_kv = (const float*)d_in[4];
    const float* W_cq = (const float*)d_in[5];
    const float* W_q = (const float*)d_in[6];
    const float* W_qr = (const float*)d_in[7];
    const float* W_kr = (const float*)d_in[8];
    const float* W_o = (const float*)d_in[9];
    const float* ln2_g = (const float*)d_in[10];
    const float* ln2_b = (const float*)d_in[11];
    const float* cent = (const float*)d_in[12];
    const float* rbias = (const float*)d_in[13];
    const float* Wg = (const float*)d_in[14];
    const float* Wu = (const float*)d_in[15];
    const float* Wd = (const float*)d_in[16];
    float* out = (float*)d_out;

    float* ws = (float*)d_ws;
    size_t off = 0;
    float* h1 = ws + off;    off += (size_t)ROWS * HDIM;
    float* c_kv = ws + off;  off += (size_t)ROWS * LDIM;
    float* c_q = ws + off;   off += (size_t)ROWS * LDIM;
    float* kv = ws + off;    off += (size_t)ROWS * 2048;
    float* q_c = ws + off;   off += (size_t)ROWS * HDIM;
    float* q_r = ws + off;   off += (size_t)ROWS * HDIM;
    float* k_r = ws + off;   off += (size_t)ROWS * RDIM;
    float* obuf = ws + off;  off += (size_t)ROWS * HDIM;
    float* xf = ws + off;    off += (size_t)ROWS * HDIM;
    float* hh = ws + off;    off += (size_t)(ROWS * 2 + 64) * DFF;
    float* route_w = ws + off; off += ROWS * 2;
    float* tok_w = ws + off;   off += ROWS * 2;
    int* ibuf = (int*)(ws + off);
    int* route_i = ibuf;           // 8192
    int* counts = ibuf + 8192;     // 8
    int* eoff = ibuf + 8200;       // 9
    int* pos = ibuf + 8212;        // 8
    int* tok_id = ibuf + 8224;     // 8192

    // 1. LN1
    ln_kernel<<<ROWS, 256, 0, stream>>>(x, ln1_g, ln1_b, h1);
    // 2-7. projections
    gemm_kernel<<<dim3(LDIM / 64, ROWS / 64), 256, 0, stream>>>(h1, W_ckv, c_kv, nullptr, ROWS, LDIM, HDIM);
    gemm_kernel<<<dim3(LDIM / 64, ROWS / 64), 256, 0, stream>>>(h1, W_cq, c_q, nullptr, ROWS, LDIM, HDIM);
    gemm_kernel<<<dim3(2048 / 64, ROWS / 64), 256, 0, stream>>>(c_kv, W_kv, kv, nullptr, ROWS, 2048, LDIM);
    gemm_kernel<<<dim3(HDIM / 64, ROWS / 64), 256, 0, stream>>>(c_q, W_q, q_c, nullptr, ROWS, HDIM, LDIM);
    gemm_kernel<<<dim3(HDIM / 64, ROWS / 64), 256, 0, stream>>>(c_q, W_qr, q_r, nullptr, ROWS, HDIM, LDIM);
    gemm_kernel<<<dim3(1, ROWS / 64), 256, 0, stream>>>(c_kv, W_kr, k_r, nullptr, ROWS, RDIM, LDIM);
    // 8. RoPE
    {
        int total_q = ROWS * NHEAD * 32;
        rope_kernel<<<(total_q + 255) / 256, 256, 0, stream>>>(q_r, NHEAD, total_q);
        int total_k = ROWS * 1 * 32;
        rope_kernel<<<(total_k + 255) / 256, 256, 0, stream>>>(k_r, 1, total_k);
    }
    // 9. flash attention -> obuf
    attn_flash_kernel<<<dim3(SEQ / 64, NHEAD, 4), 256, 0, stream>>>(q_c, q_r, kv, k_r, obuf);
    // 10. out = obuf @ W_o + x
    gemm_kernel<<<dim3(HDIM / 64, ROWS / 64), 256, 0, stream>>>(obuf, W_o, out, x, ROWS, HDIM, HDIM);
    // 11. LN2 -> xf
    ln_kernel<<<ROWS, 256, 0, stream>>>(out, ln2_g, ln2_b, xf);
    // 12. routing
    init_kernel<<<1, 64, 0, stream>>>(counts, pos);
    route_kernel<<<ROWS, 64, 0, stream>>>(xf, cent, rbias, route_i, route_w, counts);
    offsets_kernel<<<1, 1, 0, stream>>>(counts, eoff, out + (size_t)ROWS * HDIM);
    scatter_kernel<<<ROWS / 256, 256, 0, stream>>>(route_i, route_w, eoff, pos, tok_id, tok_w);
    // 13. MoE gate/up -> hh
    moe_gu_kernel<<<dim3(DFF / 64, 128, NEXP), 256, 0, stream>>>(xf, Wg, Wu, counts, eoff, tok_id, hh);
    // 14. MoE down-proj
    moe_down_kernel<<<dim3(HDIM / 64, 128, NEXP), 256, 0, stream>>>(hh, Wd, counts, eoff, tok_id, tok_w, out);
}

// Round 4
// 1699.018 us; speedup vs baseline: 3.4435x; 1.7060x over previous
//
#include <hip/hip_runtime.h>
#include <hip/hip_bf16.h>
#include <math.h>

#define SEQ 1024
#define HDIM 1024
#define NHEAD 16
#define HEADD 64
#define LDIM 256
#define RDIM 64
#define DFF 2048
#define NEXP 8
#define ROWS 4096  // B*S

typedef __attribute__((ext_vector_type(8))) short short8;
typedef __attribute__((ext_vector_type(4))) float f32x4;

// ---------------- LayerNorm ----------------
__global__ __launch_bounds__(256) void ln_kernel(const float* __restrict__ x,
                                                 const float* __restrict__ g,
                                                 const float* __restrict__ b,
                                                 float* __restrict__ out) {
    int row = blockIdx.x;
    int tid = threadIdx.x;
    __shared__ float red[256];
    __shared__ float red2[256];
    const float* xr = x + (size_t)row * HDIM;
    float s = 0.f, s2 = 0.f;
    for (int j = tid; j < HDIM; j += 256) { float v = xr[j]; s += v; s2 += v * v; }
    red[tid] = s; red2[tid] = s2; __syncthreads();
    for (int o = 128; o > 0; o >>= 1) {
        if (tid < o) { red[tid] += red[tid + o]; red2[tid] += red2[tid + o]; }
        __syncthreads();
    }
    float mean = red[0] * (1.f / HDIM);
    float var = red2[0] * (1.f / HDIM) - mean * mean;
    float inv = rsqrtf(var + 1e-5f);
    for (int j = tid; j < HDIM; j += 256) {
        out[(size_t)row * HDIM + j] = (xr[j] - mean) * inv * g[j] + b[j];
    }
}

// ---------------- Generic tiled fp32 GEMM: C = A@B (+R) ----------------
__global__ __launch_bounds__(256) void gemm_kernel(const float* __restrict__ A,
                                                   const float* __restrict__ B,
                                                   float* __restrict__ C,
                                                   const float* __restrict__ R,
                                                   int M, int N, int K) {
    __shared__ float As[16][65];
    __shared__ float Bs[16][64];
    int tid = threadIdx.x;
    int tx = tid & 15, ty = tid >> 4;
    int m0 = blockIdx.y * 64, n0 = blockIdx.x * 64;
    float acc[4][4] = {};
    for (int k0 = 0; k0 < K; k0 += 16) {
        for (int i = 0; i < 4; i++) {
            int id = tid + i * 256;
            int m = id >> 4, k = id & 15;
            As[k][m] = A[(size_t)(m0 + m) * K + k0 + k];
        }
        for (int i = 0; i < 4; i++) {
            int id = tid + i * 256;
            int k = id >> 6, n = id & 63;
            Bs[k][n] = B[(size_t)(k0 + k) * N + n0 + n];
        }
        __syncthreads();
        for (int kk = 0; kk < 16; kk++) {
            float a[4], bv[4];
            for (int i = 0; i < 4; i++) a[i] = As[kk][ty * 4 + i];
            for (int j = 0; j < 4; j++) bv[j] = Bs[kk][tx * 4 + j];
            for (int i = 0; i < 4; i++)
                for (int j = 0; j < 4; j++) acc[i][j] += a[i] * bv[j];
        }
        __syncthreads();
    }
    for (int i = 0; i < 4; i++)
        for (int j = 0; j < 4; j++) {
            size_t idx = (size_t)(m0 + ty * 4 + i) * N + n0 + tx * 4 + j;
            float v = acc[i][j];
            if (R) v += R[idx];
            C[idx] = v;
        }
}

// ---------------- RoPE (in place) ----------------
__global__ void rope_kernel(float* __restrict__ t, int heads, int total) {
    int idx = blockIdx.x * 256 + threadIdx.x;
    if (idx >= total) return;
    int i = idx & 31;
    int h = (idx >> 5) % heads;
    int row = idx / (32 * heads);
    int s = row & (SEQ - 1);
    float freq = expf(-9.210340372f * (float)i / 32.f);  // 10000^{-i/32}
    float fr = (float)s * freq;
    float sn, cs;
    sincosf(fr, &sn, &cs);
    float* p = t + (size_t)row * heads * 64 + h * 64 + 2 * i;
    float xe = p[0], xo = p[1];
    p[0] = xe * cs - xo * sn;
    p[1] = xe * sn + xo * cs;
}

// ---------------- Flash attention (fp32, tiled) ----------------
__global__ __launch_bounds__(256) void attn_flash_kernel(const float* __restrict__ qc,
                                                         const float* __restrict__ qr,
                                                         const float* __restrict__ kvbuf,
                                                         const float* __restrict__ kr,
                                                         float* __restrict__ o) {
    int qt = blockIdx.x, h = blockIdx.y, b = blockIdx.z;
    int tid = threadIdx.x;
    int tx = tid & 15, ty = tid >> 4;
    __shared__ float SA[64][68];
    __shared__ float Vs[64][68];
    float acc[4][4] = {};
    float mrow[4], lrow[4];
    for (int i = 0; i < 4; i++) { mrow[i] = -1e30f; lrow[i] = 0.f; }
    int q0 = qt * 64;
    size_t brow = (size_t)b * SEQ;

    for (int kt = 0; kt <= qt; ++kt) {
        int k0 = kt * 64;
        float s[4][4] = {};
        for (int dc = 0; dc < 4; ++dc) {
            int dbase = dc * 32;
            __syncthreads();
            #pragma unroll
            for (int it = 0; it < 8; ++it) {
                int id = tid + it * 256;
                int d = id & 31, r = id >> 5;
                float qv, kval;
                if (dbase < 64) {
                    qv = qc[(brow + q0 + r) * HDIM + h * 64 + dbase + d];
                    kval = kvbuf[(brow + k0 + r) * 2048 + h * 64 + dbase + d];
                } else {
                    qv = qr[(brow + q0 + r) * HDIM + h * 64 + (dbase - 64) + d];
                    kval = kr[(brow + k0 + r) * 64 + (dbase - 64) + d];
                }
                SA[d][r] = qv;
                SA[32 + d][r] = kval;
            }
            __syncthreads();
            #pragma unroll 4
            for (int kk = 0; kk < 32; ++kk) {
                float a0 = SA[kk][ty * 4 + 0];
                float a1 = SA[kk][ty * 4 + 1];
                float a2 = SA[kk][ty * 4 + 2];
                float a3 = SA[kk][ty * 4 + 3];
                float b0 = SA[32 + kk][tx * 4 + 0];
                float b1 = SA[32 + kk][tx * 4 + 1];
                float b2 = SA[32 + kk][tx * 4 + 2];
                float b3 = SA[32 + kk][tx * 4 + 3];
                s[0][0] += a0 * b0; s[0][1] += a0 * b1; s[0][2] += a0 * b2; s[0][3] += a0 * b3;
                s[1][0] += a1 * b0; s[1][1] += a1 * b1; s[1][2] += a1 * b2; s[1][3] += a1 * b3;
                s[2][0] += a2 * b0; s[2][1] += a2 * b1; s[2][2] += a2 * b2; s[2][3] += a2 * b3;
                s[3][0] += a3 * b0; s[3][1] += a3 * b1; s[3][2] += a3 * b2; s[3][3] += a3 * b3;
            }
        }
        #pragma unroll
        for (int i = 0; i < 4; i++)
            #pragma unroll
            for (int j = 0; j < 4; j++) {
                s[i][j] *= 0.125f;
                if (kt == qt && (k0 + tx * 4 + j) > (q0 + ty * 4 + i)) s[i][j] = -1e30f;
            }
        float p[4][4];
        #pragma unroll
        for (int i = 0; i < 4; i++) {
            float tmax = fmaxf(fmaxf(s[i][0], s[i][1]), fmaxf(s[i][2], s[i][3]));
            tmax = fmaxf(tmax, __shfl_xor(tmax, 1));
            tmax = fmaxf(tmax, __shfl_xor(tmax, 2));
            tmax = fmaxf(tmax, __shfl_xor(tmax, 4));
            tmax = fmaxf(tmax, __shfl_xor(tmax, 8));
            float mnew = fmaxf(mrow[i], tmax);
            float psum = 0.f;
            #pragma unroll
            for (int j = 0; j < 4; j++) { p[i][j] = expf(s[i][j] - mnew); psum += p[i][j]; }
            psum += __shfl_xor(psum, 1);
            psum += __shfl_xor(psum, 2);
            psum += __shfl_xor(psum, 4);
            psum += __shfl_xor(psum, 8);
            float factor = expf(mrow[i] - mnew);
            lrow[i] = lrow[i] * factor + psum;
            #pragma unroll
            for (int j = 0; j < 4; j++) acc[i][j] *= factor;
            mrow[i] = mnew;
        }
        __syncthreads();
        #pragma unroll
        for (int i = 0; i < 4; i++)
            #pragma unroll
            for (int j = 0; j < 4; j++) SA[ty * 4 + i][tx * 4 + j] = p[i][j];
        #pragma unroll
        for (int it = 0; it < 16; ++it) {
            int id = tid + it * 256;
            int d = id & 63, r = id >> 6;
            Vs[r][d] = kvbuf[(brow + k0 + r) * 2048 + 1024 + h * 64 + d];
        }
        __syncthreads();
        #pragma unroll 4
        for (int kk = 0; kk < 64; ++kk) {
            float v0 = Vs[kk][tx * 4 + 0];
            float v1 = Vs[kk][tx * 4 + 1];
            float v2 = Vs[kk][tx * 4 + 2];
            float v3 = Vs[kk][tx * 4 + 3];
            #pragma unroll
            for (int i = 0; i < 4; i++) {
                float pb = SA[ty * 4 + i][kk];
                acc[i][0] += pb * v0; acc[i][1] += pb * v1; acc[i][2] += pb * v2; acc[i][3] += pb * v3;
            }
        }
    }
    #pragma unroll
    for (int i = 0; i < 4; i++) {
        float inv = 1.f / lrow[i];
        #pragma unroll
        for (int j = 0; j < 4; j++) {
            o[(brow + q0 + ty * 4 + i) * HDIM + h * 64 + tx * 4 + j] = acc[i][j] * inv;
        }
    }
}

// ---------------- converters ----------------
// fp32 [K][N] -> bf16 [N][K], per-expert (z)
__global__ __launch_bounds__(256) void transpose_bf16_kernel(const float* __restrict__ src,
                                                             __hip_bfloat16* __restrict__ dst,
                                                             int K, int N) {
    int n0 = blockIdx.x * 64, k0 = blockIdx.y * 64;
    size_t eo = (size_t)blockIdx.z * K * N;
    src += eo; dst += eo;
    __shared__ float t[64][65];
    int tid = threadIdx.x;
    #pragma unroll
    for (int i = 0; i < 16; i++) {
        int id = tid + i * 256;
        int r = id >> 6, cn = id & 63;
        t[r][cn] = src[(size_t)(k0 + r) * N + n0 + cn];
    }
    __syncthreads();
    #pragma unroll
    for (int i = 0; i < 16; i++) {
        int id = tid + i * 256;
        int rn = id >> 6, ck = id & 63;
        dst[(size_t)(n0 + rn) * K + k0 + ck] = __float2bfloat16(t[ck][rn]);
    }
}

// fp32 -> bf16 elementwise (n multiple of 1024)
__global__ __launch_bounds__(256) void cvt_bf16_kernel(const float* __restrict__ src,
                                                       __hip_bfloat16* __restrict__ dst) {
    int i = (blockIdx.x * 256 + threadIdx.x) * 4;
    float4 v = *(const float4*)(src + i);
    union { unsigned long long u; __hip_bfloat16 b[4]; } cv;
    cv.b[0] = __float2bfloat16(v.x);
    cv.b[1] = __float2bfloat16(v.y);
    cv.b[2] = __float2bfloat16(v.z);
    cv.b[3] = __float2bfloat16(v.w);
    *(unsigned long long*)(dst + i) = cv.u;
}

// ---------------- zero small int scratch ----------------
__global__ void init_kernel(int* counts, int* pos) {
    int t = threadIdx.x;
    if (t < NEXP) { counts[t] = 0; pos[t] = 0; }
}

// ---------------- Routing: one wave per row ----------------
__global__ __launch_bounds__(64) void route_kernel(const float* __restrict__ xf,
                                                   const float* __restrict__ cent,
                                                   const float* __restrict__ rbias,
                                                   int* __restrict__ route_i,
                                                   float* __restrict__ route_w,
                                                   int* __restrict__ counts) {
    int row = blockIdx.x;
    int lane = threadIdx.x;
    const float* xr = xf + (size_t)row * HDIM;
    float p[NEXP] = {};
    for (int j = lane; j < HDIM; j += 64) {
        float xv = xr[j];
        for (int e = 0; e < NEXP; e++) p[e] += xv * cent[e * HDIM + j];
    }
    for (int e = 0; e < NEXP; e++) {
        float v = p[e];
        for (int o = 32; o > 0; o >>= 1) v += __shfl_down(v, o);
        p[e] = v;
    }
    if (lane == 0) {
        float biased[NEXP];
        for (int e = 0; e < NEXP; e++) {
            float aff = 1.f / (1.f + expf(-p[e]));
            biased[e] = aff + rbias[e];
        }
        int i0 = 0; float v0 = biased[0];
        for (int e = 1; e < NEXP; e++) if (biased[e] > v0) { v0 = biased[e]; i0 = e; }
        int i1 = -1; float v1 = -1e30f;
        for (int e = 0; e < NEXP; e++) if (e != i0 && biased[e] > v1) { v1 = biased[e]; i1 = e; }
        float e1 = expf(v1 - v0);
        float wsum = 1.f + e1;
        route_i[row * 2] = i0; route_i[row * 2 + 1] = i1;
        route_w[row * 2] = 1.f / wsum; route_w[row * 2 + 1] = e1 / wsum;
        atomicAdd(&counts[i0], 1);
        atomicAdd(&counts[i1], 1);
    }
}

__global__ void offsets_kernel(const int* counts, int* eoff, float* out_counts) {
    int acc = 0;
    for (int e = 0; e < NEXP; e++) { eoff[e] = acc; acc += counts[e]; out_counts[e] = (float)counts[e]; }
    eoff[NEXP] = acc;
}

__global__ void scatter_kernel(const int* route_i, const float* route_w, const int* eoff,
                               int* pos, int* tok_id, float* tok_w) {
    int row = blockIdx.x * 256 + threadIdx.x;
    if (row >= ROWS) return;
    for (int sl = 0; sl < 2; sl++) {
        int e = route_i[row * 2 + sl];
        int p = atomicAdd(&pos[e], 1);
        int dst = eoff[e] + p;
        tok_id[dst] = row;
        tok_w[dst] = route_w[row * 2 + sl];
    }
}

// ---------------- MoE gate/up, bf16 MFMA ----------------
// grid: (DFF/64=32, 32, NEXP). block 256 = 4 waves (2x2).
// Tile: 128 tokens x 64 dff, BK=64. A gathered from xf_bf; B from transposed weights.
__global__ __launch_bounds__(256) void moe_gu_mfma(const __hip_bfloat16* __restrict__ xf_bf,
                                                   const __hip_bfloat16* __restrict__ Wg_t,
                                                   const __hip_bfloat16* __restrict__ Wu_t,
                                                   const int* __restrict__ counts,
                                                   const int* __restrict__ eoff,
                                                   const int* __restrict__ tok_id,
                                                   __hip_bfloat16* __restrict__ hh) {
    int e = blockIdx.z;
    int n_e = counts[e];
    int t0 = blockIdx.y * 128;
    if (t0 >= n_e) return;
    int n0 = blockIdx.x * 64;
    __shared__ short As[128 * 64];   // [row][chunk-swizzled], 128B rows
    __shared__ short Bgs[64 * 64];
    __shared__ short Bus[64 * 64];
    __shared__ int toks[128];
    int tid = threadIdx.x;
    int lane = tid & 63, w = tid >> 6;
    int wr = w >> 1, wc = w & 1;     // wave tile: 64 tok x 32 dff
    if (tid < 128) {
        int idx = t0 + tid;
        toks[tid] = (idx < n_e) ? tok_id[eoff[e] + idx] : 0;
    }
    __syncthreads();
    f32x4 accg[4][2] = {};
    f32x4 accu[4][2] = {};
    const __hip_bfloat16* Wge = Wg_t + (size_t)e * DFF * HDIM;
    const __hip_bfloat16* Wue = Wu_t + (size_t)e * DFF * HDIM;
    for (int k0 = 0; k0 < HDIM; k0 += 64) {
        // stage A: 1024 x 16B chunks, XOR-swizzled within each 128B row
        #pragma unroll
        for (int rr = 0; rr < 4; rr++) {
            int chunk = tid + rr * 256;
            int row = chunk >> 3, p = chunk & 7;
            int c = p ^ (row & 7);
            *(short8*)(&As[chunk * 8]) =
                *(const short8*)((const short*)xf_bf + (size_t)toks[row] * HDIM + k0 + c * 8);
        }
        // stage Bg/Bu: 512 chunks each
        #pragma unroll
        for (int rr = 0; rr < 2; rr++) {
            int chunk = tid + rr * 256;
            int row = chunk >> 3, p = chunk & 7;
            int c = p ^ (row & 7);
            *(short8*)(&Bgs[chunk * 8]) =
                *(const short8*)((const short*)Wge + (size_t)(n0 + row) * HDIM + k0 + c * 8);
            *(short8*)(&Bus[chunk * 8]) =
                *(const short8*)((const short*)Wue + (size_t)(n0 + row) * HDIM + k0 + c * 8);
        }
        __syncthreads();
        #pragma unroll
        for (int kk = 0; kk < 2; kk++) {
            short8 a[4], bg[2], bu[2];
            #pragma unroll
            for (int i = 0; i < 4; i++) {
                int row = wr * 64 + i * 16 + (lane & 15);
                int c = (kk * 4 + (lane >> 4)) ^ (row & 7);
                a[i] = *(const short8*)(&As[row * 64 + c * 8]);
            }
            #pragma unroll
            for (int j = 0; j < 2; j++) {
                int row = wc * 32 + j * 16 + (lane & 15);
                int c = (kk * 4 + (lane >> 4)) ^ (row & 7);
                bg[j] = *(const short8*)(&Bgs[row * 64 + c * 8]);
                bu[j] = *(const short8*)(&Bus[row * 64 + c * 8]);
            }
            #pragma unroll
            for (int i = 0; i < 4; i++)
                #pragma unroll
                for (int j = 0; j < 2; j++) {
                    accg[i][j] = __builtin_amdgcn_mfma_f32_16x16x32_bf16(a[i], bg[j], accg[i][j], 0, 0, 0);
                    accu[i][j] = __builtin_amdgcn_mfma_f32_16x16x32_bf16(a[i], bu[j], accu[i][j], 0, 0, 0);
                }
        }
        __syncthreads();
    }
    // epilogue: silu(g)*u -> hh (bf16)
    #pragma unroll
    for (int i = 0; i < 4; i++) {
        #pragma unroll
        for (int r = 0; r < 4; r++) {
            int row = wr * 64 + i * 16 + (lane >> 4) * 4 + r;
            if (t0 + row < n_e) {
                size_t slot = (size_t)eoff[e] + t0 + row;
                #pragma unroll
                for (int j = 0; j < 2; j++) {
                    float g = accg[i][j][r];
                    float u = accu[i][j][r];
                    float val = g / (1.f + __expf(-g)) * u;
                    hh[slot * DFF + n0 + wc * 32 + j * 16 + (lane & 15)] = __float2bfloat16(val);
                }
            }
        }
    }
}

// ---------------- MoE down, bf16 MFMA ----------------
// grid: (HDIM/128=8, 32, NEXP). block 256 = 4 waves (2x2).
// Tile: 128 slots x 128 hdim, BK=64, K=DFF. atomicAdd into out.
__global__ __launch_bounds__(256) void moe_down_mfma(const __hip_bfloat16* __restrict__ hh,
                                                     const __hip_bfloat16* __restrict__ Wd_t,
                                                     const int* __restrict__ counts,
                                                     const int* __restrict__ eoff,
                                                     const int* __restrict__ tok_id,
                                                     const float* __restrict__ tok_w,
                                                     float* __restrict__ out) {
    int e = blockIdx.z;
    int n_e = counts[e];
    int t0 = blockIdx.y * 128;
    if (t0 >= n_e) return;
    int n0 = blockIdx.x * 128;
    __shared__ short As[128 * 64];
    __shared__ short Bs[128 * 64];
    int tid = threadIdx.x;
    int lane = tid & 63, w = tid >> 6;
    int wr = w >> 1, wc = w & 1;     // wave tile: 64 slots x 64 hdim
    f32x4 acc[4][4] = {};
    const __hip_bfloat16* Ae = hh + (size_t)(eoff[e] + t0) * DFF;
    const __hip_bfloat16* Be = Wd_t + (size_t)e * HDIM * DFF;
    for (int k0 = 0; k0 < DFF; k0 += 64) {
        #pragma unroll
        for (int rr = 0; rr < 4; rr++) {
            int chunk = tid + rr * 256;
            int row = chunk >> 3, p = chunk & 7;
            int c = p ^ (row & 7);
            *(short8*)(&As[chunk * 8]) =
                *(const short8*)((const short*)Ae + (size_t)row * DFF + k0 + c * 8);
            *(short8*)(&Bs[chunk * 8]) =
                *(const short8*)((const short*)Be + (size_t)(n0 + row) * DFF + k0 + c * 8);
        }
        __syncthreads();
        #pragma unroll
        for (int kk = 0; kk < 2; kk++) {
            short8 a[4], bv[4];
            #pragma unroll
            for (int i = 0; i < 4; i++) {
                int row = wr * 64 + i * 16 + (lane & 15);
                int c = (kk * 4 + (lane >> 4)) ^ (row & 7);
                a[i] = *(const short8*)(&As[row * 64 + c * 8]);
            }
            #pragma unroll
            for (int j = 0; j < 4; j++) {
                int row = wc * 64 + j * 16 + (lane & 15);
                int c = (kk * 4 + (lane >> 4)) ^ (row & 7);
                bv[j] = *(const short8*)(&Bs[row * 64 + c * 8]);
            }
            #pragma unroll
            for (int i = 0; i < 4; i++)
                #pragma unroll
                for (int j = 0; j < 4; j++)
                    acc[i][j] = __builtin_amdgcn_mfma_f32_16x16x32_bf16(a[i], bv[j], acc[i][j], 0, 0, 0);
        }
        __syncthreads();
    }
    #pragma unroll
    for (int i = 0; i < 4; i++) {
        #pragma unroll
        for (int r = 0; r < 4; r++) {
            int row = wr * 64 + i * 16 + (lane >> 4) * 4 + r;
            if (t0 + row < n_e) {
                int slot = eoff[e] + t0 + row;
                int tok = tok_id[slot];
                float tw = tok_w[slot];
                #pragma unroll
                for (int j = 0; j < 4; j++) {
                    int col = n0 + wc * 64 + j * 16 + (lane & 15);
                    atomicAdd(&out[(size_t)tok * HDIM + col], tw * acc[i][j][r]);
                }
            }
        }
    }
}

extern "C" void kernel_launch(void* const* d_in, const int* in_sizes, int n_in,
                              void* d_out, int out_size, void* d_ws, size_t ws_size,
                              hipStream_t stream) {
    const float* x = (const float*)d_in[0];
    const float* ln1_g = (const float*)d_in[1];
    const float* ln1_b = (const float*)d_in[2];
    const float* W_ckv = (const float*)d_in[3];
    const float* W_kv = (const float*)d_in[4];
    const float* W_cq = (const float*)d_in[5];
    const float* W_q = (const float*)d_in[6];
    const float* W_qr = (const float*)d_in[7];
    const float* W_kr = (const float*)d_in[8];
    const float* W_o = (const float*)d_in[9];
    const float* ln2_g = (const float*)d_in[10];
    const float* ln2_b = (const float*)d_in[11];
    const float* cent = (const float*)d_in[12];
    const float* rbias = (const float*)d_in[13];
    const float* Wg = (const float*)d_in[14];
    const float* Wu = (const float*)d_in[15];
    const float* Wd = (const float*)d_in[16];
    float* out = (float*)d_out;

    float* ws = (float*)d_ws;
    size_t off = 0;
    float* h1 = ws + off;    off += (size_t)ROWS * HDIM;   // 4.19M
    float* c_kv = ws + off;  off += (size_t)ROWS * LDIM;
    float* c_q = ws + off;   off += (size_t)ROWS * LDIM;
    float* kv = ws + off;    off += (size_t)ROWS * 2048;
    float* q_c = ws + off;   off += (size_t)ROWS * HDIM;
    float* q_r = ws + off;   off += (size_t)ROWS * HDIM;
    float* k_r = ws + off;   off += (size_t)ROWS * RDIM;
    float* obuf = ws + off;  off += (size_t)ROWS * HDIM;
    // --- bf16 alias region over [h1 .. obuf] (written only after W_o GEMM) ---
    {
        // region size check: 27.26M floats needed <= 27.51M available
    }
    __hip_bfloat16* Wg_t = (__hip_bfloat16*)h1;                    // 8*2048*1024 bf16 = 8.39M floats
    __hip_bfloat16* Wu_t = Wg_t + (size_t)NEXP * DFF * HDIM;
    __hip_bfloat16* Wd_t = Wu_t + (size_t)NEXP * DFF * HDIM;
    __hip_bfloat16* xf_bf = Wd_t + (size_t)NEXP * HDIM * DFF;      // 4.19M bf16
    // --- non-aliased tail ---
    float* xf = ws + off;    off += (size_t)ROWS * HDIM;
    __hip_bfloat16* hh = (__hip_bfloat16*)(ws + off); off += (size_t)(ROWS * 2 + 128) * DFF / 2;
    float* route_w = ws + off; off += ROWS * 2;
    float* tok_w = ws + off;   off += ROWS * 2;
    int* ibuf = (int*)(ws + off);
    int* route_i = ibuf;           // 8192
    int* counts = ibuf + 8192;     // 8
    int* eoff = ibuf + 8200;       // 9
    int* pos = ibuf + 8212;        // 8
    int* tok_id = ibuf + 8224;     // 8192

    // 1. LN1
    ln_kernel<<<ROWS, 256, 0, stream>>>(x, ln1_g, ln1_b, h1);
    // 2-7. projections (fp32)
    gemm_kernel<<<dim3(LDIM / 64, ROWS / 64), 256, 0, stream>>>(h1, W_ckv, c_kv, nullptr, ROWS, LDIM, HDIM);
    gemm_kernel<<<dim3(LDIM / 64, ROWS / 64), 256, 0, stream>>>(h1, W_cq, c_q, nullptr, ROWS, LDIM, HDIM);
    gemm_kernel<<<dim3(2048 / 64, ROWS / 64), 256, 0, stream>>>(c_kv, W_kv, kv, nullptr, ROWS, 2048, LDIM);
    gemm_kernel<<<dim3(HDIM / 64, ROWS / 64), 256, 0, stream>>>(c_q, W_q, q_c, nullptr, ROWS, HDIM, LDIM);
    gemm_kernel<<<dim3(HDIM / 64, ROWS / 64), 256, 0, stream>>>(c_q, W_qr, q_r, nullptr, ROWS, HDIM, LDIM);
    gemm_kernel<<<dim3(1, ROWS / 64), 256, 0, stream>>>(c_kv, W_kr, k_r, nullptr, ROWS, RDIM, LDIM);
    // 8. RoPE
    {
        int total_q = ROWS * NHEAD * 32;
        rope_kernel<<<(total_q + 255) / 256, 256, 0, stream>>>(q_r, NHEAD, total_q);
        int total_k = ROWS * 1 * 32;
        rope_kernel<<<(total_k + 255) / 256, 256, 0, stream>>>(k_r, 1, total_k);
    }
    // 9. flash attention -> obuf
    attn_flash_kernel<<<dim3(SEQ / 64, NHEAD, 4), 256, 0, stream>>>(q_c, q_r, kv, k_r, obuf);
    // 10. out = obuf @ W_o + x
    gemm_kernel<<<dim3(HDIM / 64, ROWS / 64), 256, 0, stream>>>(obuf, W_o, out, x, ROWS, HDIM, HDIM);
    // 11. LN2 -> xf
    ln_kernel<<<ROWS, 256, 0, stream>>>(out, ln2_g, ln2_b, xf);
    // 12. converters (alias region now free)
    transpose_bf16_kernel<<<dim3(DFF / 64, HDIM / 64, NEXP), 256, 0, stream>>>(Wg, Wg_t, HDIM, DFF);
    transpose_bf16_kernel<<<dim3(DFF / 64, HDIM / 64, NEXP), 256, 0, stream>>>(Wu, Wu_t, HDIM, DFF);
    transpose_bf16_kernel<<<dim3(HDIM / 64, DFF / 64, NEXP), 256, 0, stream>>>(Wd, Wd_t, DFF, HDIM);
    cvt_bf16_kernel<<<(ROWS * HDIM / 4) / 256, 256, 0, stream>>>(xf, xf_bf);
    // 13. routing
    init_kernel<<<1, 64, 0, stream>>>(counts, pos);
    route_kernel<<<ROWS, 64, 0, stream>>>(xf, cent, rbias, route_i, route_w, counts);
    offsets_kernel<<<1, 1, 0, stream>>>(counts, eoff, out + (size_t)ROWS * HDIM);
    scatter_kernel<<<ROWS / 256, 256, 0, stream>>>(route_i, route_w, eoff, pos, tok_id, tok_w);
    // 14. MoE gate/up -> hh (bf16 MFMA)
    moe_gu_mfma<<<dim3(DFF / 64, 32, NEXP), 256, 0, stream>>>(xf_bf, Wg_t, Wu_t, counts, eoff, tok_id, hh);
    // 15. MoE down-proj (bf16 MFMA, atomic accumulate)
    moe_down_mfma<<<dim3(HDIM / 128, 32, NEXP), 256, 0, stream>>>(hh, Wd_t, counts, eoff, tok_id, tok_w, out);
}

// Round 5
// 918.432 us; speedup vs baseline: 6.3701x; 1.8499x over previous
//
#include <hip/hip_runtime.h>
#include <hip/hip_bf16.h>
#include <math.h>

#define SEQ 1024
#define HDIM 1024
#define NHEAD 16
#define HEADD 64
#define LDIM 256
#define RDIM 64
#define DFF 2048
#define NEXP 8
#define ROWS 4096  // B*S

typedef __attribute__((ext_vector_type(8))) short short8;
typedef __attribute__((ext_vector_type(4))) float f32x4;

static __device__ __forceinline__ short f2bf_s(float v) {
    __hip_bfloat16 hb = __float2bfloat16(v);
    return *reinterpret_cast<short*>(&hb);
}

// ---------------- LayerNorm (fp32 in, fp32 and/or bf16 out) ----------------
__global__ __launch_bounds__(256) void ln_kernel(const float* __restrict__ x,
                                                 const float* __restrict__ g,
                                                 const float* __restrict__ b,
                                                 float* __restrict__ out_f,
                                                 __hip_bfloat16* __restrict__ out_bf) {
    int row = blockIdx.x;
    int tid = threadIdx.x;
    __shared__ float red[256];
    __shared__ float red2[256];
    const float* xr = x + (size_t)row * HDIM;
    float s = 0.f, s2 = 0.f;
    for (int j = tid; j < HDIM; j += 256) { float v = xr[j]; s += v; s2 += v * v; }
    red[tid] = s; red2[tid] = s2; __syncthreads();
    for (int o = 128; o > 0; o >>= 1) {
        if (tid < o) { red[tid] += red[tid + o]; red2[tid] += red2[tid + o]; }
        __syncthreads();
    }
    float mean = red[0] * (1.f / HDIM);
    float var = red2[0] * (1.f / HDIM) - mean * mean;
    float inv = rsqrtf(var + 1e-5f);
    for (int j = tid; j < HDIM; j += 256) {
        float v = (xr[j] - mean) * inv * g[j] + b[j];
        if (out_f) out_f[(size_t)row * HDIM + j] = v;
        if (out_bf) out_bf[(size_t)row * HDIM + j] = __float2bfloat16(v);
    }
}

// ---------------- weight transpose+convert: fp32 [K][N] -> bf16 [N][K] (x scale) ----------------
__global__ __launch_bounds__(256) void transpose_bf16_kernel(const float* __restrict__ src,
                                                             __hip_bfloat16* __restrict__ dst,
                                                             int K, int N, float scale) {
    int n0 = blockIdx.x * 64, k0 = blockIdx.y * 64;
    size_t eo = (size_t)blockIdx.z * K * N;
    src += eo; dst += eo;
    __shared__ float t[64][65];
    int tid = threadIdx.x;
    #pragma unroll
    for (int i = 0; i < 16; i++) {
        int id = tid + i * 256;
        int r = id >> 6, cn = id & 63;
        t[r][cn] = src[(size_t)(k0 + r) * N + n0 + cn];
    }
    __syncthreads();
    #pragma unroll
    for (int i = 0; i < 16; i++) {
        int id = tid + i * 256;
        int rn = id >> 6, ck = id & 63;
        dst[(size_t)(n0 + rn) * K + k0 + ck] = __float2bfloat16(t[ck][rn] * scale);
    }
}

// fp32 -> bf16 elementwise (n multiple of 1024)
__global__ __launch_bounds__(256) void cvt_bf16_kernel(const float* __restrict__ src,
                                                       __hip_bfloat16* __restrict__ dst) {
    int i = (blockIdx.x * 256 + threadIdx.x) * 4;
    float4 v = *(const float4*)(src + i);
    union { unsigned long long u; __hip_bfloat16 b[4]; } cv;
    cv.b[0] = __float2bfloat16(v.x);
    cv.b[1] = __float2bfloat16(v.y);
    cv.b[2] = __float2bfloat16(v.z);
    cv.b[3] = __float2bfloat16(v.w);
    *(unsigned long long*)(dst + i) = cv.u;
}

// ---------------- generic bf16 MFMA GEMM ----------------
// C[M][N] = A[M][K] @ Bt[N][K]^T. grid (N/128, M/128), 256 thr = 4 waves (2x2), wave=64x64.
// mode 0: row-major, write Cf (+R) and/or Cbf. mode 1: PACK_LO (bf16 [b,h,s,128] d=0..63).
// mode 2: PACK_HI (d=64..127).
__global__ __launch_bounds__(256) void gemm_bf16_kernel(const __hip_bfloat16* __restrict__ A,
                                                        const __hip_bfloat16* __restrict__ Bt,
                                                        float* __restrict__ Cf,
                                                        __hip_bfloat16* __restrict__ Cbf,
                                                        const float* __restrict__ R,
                                                        int M, int N, int K, int mode) {
    int m0 = blockIdx.y * 128, n0 = blockIdx.x * 128;
    __shared__ short As[128 * 64];
    __shared__ short Bs[128 * 64];
    int tid = threadIdx.x;
    int lane = tid & 63, w = tid >> 6;
    int wr = w >> 1, wc = w & 1;
    int lm = lane & 15, g = lane >> 4;
    f32x4 acc[4][4] = {};
    for (int k0 = 0; k0 < K; k0 += 64) {
        #pragma unroll
        for (int rr = 0; rr < 4; rr++) {
            int cid = tid + rr * 256;
            int row = cid >> 3, p = cid & 7;
            int c = p ^ (row & 7);
            *(short8*)(&As[cid * 8]) = *(const short8*)((const short*)A + (size_t)(m0 + row) * K + k0 + c * 8);
            *(short8*)(&Bs[cid * 8]) = *(const short8*)((const short*)Bt + (size_t)(n0 + row) * K + k0 + c * 8);
        }
        __syncthreads();
        #pragma unroll
        for (int kk = 0; kk < 2; kk++) {
            short8 a[4], bv[4];
            #pragma unroll
            for (int i = 0; i < 4; i++) {
                int row = wr * 64 + i * 16 + lm;
                int c = (kk * 4 + g) ^ (row & 7);
                a[i] = *(const short8*)(&As[row * 64 + c * 8]);
            }
            #pragma unroll
            for (int j = 0; j < 4; j++) {
                int row = wc * 64 + j * 16 + lm;
                int c = (kk * 4 + g) ^ (row & 7);
                bv[j] = *(const short8*)(&Bs[row * 64 + c * 8]);
            }
            #pragma unroll
            for (int i = 0; i < 4; i++)
                #pragma unroll
                for (int j = 0; j < 4; j++)
                    acc[i][j] = __builtin_amdgcn_mfma_f32_16x16x32_bf16(a[i], bv[j], acc[i][j], 0, 0, 0);
        }
        __syncthreads();
    }
    #pragma unroll
    for (int i = 0; i < 4; i++) {
        #pragma unroll
        for (int r = 0; r < 4; r++) {
            int m = m0 + wr * 64 + i * 16 + g * 4 + r;
            #pragma unroll
            for (int j = 0; j < 4; j++) {
                int n = n0 + wc * 64 + j * 16 + lm;
                float v = acc[i][j][r];
                if (mode == 0) {
                    size_t idx = (size_t)m * N + n;
                    if (R) v += R[idx];
                    if (Cf) Cf[idx] = v;
                    if (Cbf) Cbf[idx] = __float2bfloat16(v);
                } else {
                    size_t idx = ((size_t)((m >> 10) * 16 + (n >> 6)) * SEQ + (m & 1023)) * 128
                               + (n & 63) + (mode == 2 ? 64 : 0);
                    Cbf[idx] = __float2bfloat16(v);
                }
            }
        }
    }
}

// ---------------- tiny k_r GEMM: [4096][256] @ [64][256]^T -> bf16 [4096][64] ----------------
__global__ __launch_bounds__(256) void gemm_kr_kernel(const __hip_bfloat16* __restrict__ A,
                                                      const __hip_bfloat16* __restrict__ Bt,
                                                      __hip_bfloat16* __restrict__ C) {
    int m0 = blockIdx.x * 64;
    int tid = threadIdx.x;
    int lane = tid & 63, w = tid >> 6;
    int lm = lane & 15, g = lane >> 4;
    f32x4 acc[4] = {};
    const short* Ab = (const short*)A + (size_t)(m0 + w * 16 + lm) * 256;
    #pragma unroll
    for (int ks = 0; ks < 8; ks++) {
        short8 a = *(const short8*)(Ab + ks * 32 + g * 8);
        #pragma unroll
        for (int j = 0; j < 4; j++) {
            short8 b = *(const short8*)((const short*)Bt + (size_t)(j * 16 + lm) * 256 + ks * 32 + g * 8);
            acc[j] = __builtin_amdgcn_mfma_f32_16x16x32_bf16(a, b, acc[j], 0, 0, 0);
        }
    }
    #pragma unroll
    for (int r = 0; r < 4; r++)
        #pragma unroll
        for (int j = 0; j < 4; j++)
            C[(size_t)(m0 + w * 16 + g * 4 + r) * 64 + j * 16 + lm] = __float2bfloat16(acc[j][r]);
}

// ---------------- RoPE on packed q_bf HI half (in place, bf16) ----------------
__global__ void rope_q_kernel(__hip_bfloat16* __restrict__ q_bf) {
    int idx = blockIdx.x * 256 + threadIdx.x;   // [bh(6b)|s(10b)|i(5b)]
    int i = idx & 31;
    int s = (idx >> 5) & 1023;
    int bh = idx >> 15;
    float freq = __expf(-9.210340372f * (float)i / 32.f);
    float fr = (float)s * freq;
    float sn, cs;
    __sincosf(fr, &sn, &cs);
    __hip_bfloat16* p = q_bf + ((size_t)bh * SEQ + s) * 128 + 64 + 2 * i;
    float xe = __bfloat162float(p[0]), xo = __bfloat162float(p[1]);
    p[0] = __float2bfloat16(xe * cs - xo * sn);
    p[1] = __float2bfloat16(xe * sn + xo * cs);
}

// ---------------- RoPE k_r + broadcast-pack into k_bf HI ----------------
__global__ void rope_pack_kr_kernel(const __hip_bfloat16* __restrict__ k_r_bf,
                                    __hip_bfloat16* __restrict__ k_bf) {
    int idx = blockIdx.x * 256 + threadIdx.x;   // [row(12b)|i(5b)]
    int i = idx & 31;
    int row = idx >> 5;          // b*SEQ + s
    int s = row & 1023, b = row >> 10;
    float freq = __expf(-9.210340372f * (float)i / 32.f);
    float fr = (float)s * freq;
    float sn, cs;
    __sincosf(fr, &sn, &cs);
    float xe = __bfloat162float(k_r_bf[(size_t)row * 64 + 2 * i]);
    float xo = __bfloat162float(k_r_bf[(size_t)row * 64 + 2 * i + 1]);
    __hip_bfloat16 re = __float2bfloat16(xe * cs - xo * sn);
    __hip_bfloat16 ro = __float2bfloat16(xe * sn + xo * cs);
    #pragma unroll
    for (int h = 0; h < NHEAD; h++) {
        size_t base = ((size_t)(b * 16 + h) * SEQ + s) * 128 + 64 + 2 * i;
        k_bf[base] = re;
        k_bf[base + 1] = ro;
    }
}

// ---------------- V transpose: v_bf [b*s][h*64+d] -> vt_bf [b,h,d,s] ----------------
__global__ __launch_bounds__(256) void pack_vt_kernel(const __hip_bfloat16* __restrict__ v_bf,
                                                      __hip_bfloat16* __restrict__ vt_bf) {
    int s0 = blockIdx.x * 64, h = blockIdx.y, b = blockIdx.z;
    __shared__ short t[64][72];
    int tid = threadIdx.x;
    #pragma unroll
    for (int i = 0; i < 16; i++) {
        int id = tid + i * 256;
        int r = id >> 6, d = id & 63;
        t[r][d] = ((const short*)v_bf)[(size_t)(b * SEQ + s0 + r) * HDIM + h * 64 + d];
    }
    __syncthreads();
    #pragma unroll
    for (int i = 0; i < 16; i++) {
        int id = tid + i * 256;
        int d = id >> 6, cs = id & 63;
        ((short*)vt_bf)[((size_t)(b * 16 + h) * 64 + d) * SEQ + s0 + cs] = t[cs][d];
    }
}

// ---------------- MFMA flash attention ----------------
// grid (SEQ/64, NHEAD, B), 256 thr = 4 waves; wave w owns q-rows [qt*64+w*16, +16).
// q_bf [bh,s,128] pre-scaled; k_bf [bh,s,128]; vt_bf [bh,64,s]; out bf16 [b*s][h*64+d].
__global__ __launch_bounds__(256) void attn_mfma_kernel(const __hip_bfloat16* __restrict__ q_bf,
                                                        const __hip_bfloat16* __restrict__ k_bf,
                                                        const __hip_bfloat16* __restrict__ vt_bf,
                                                        __hip_bfloat16* __restrict__ obuf) {
    int qt = blockIdx.x, h = blockIdx.y, b = blockIdx.z;
    int bh = b * NHEAD + h;
    int tid = threadIdx.x;
    int lane = tid & 63, w = tid >> 6;
    int lm = lane & 15, g = lane >> 4;
    __shared__ short Ks[64 * 128];   // [key][d], 16-chunk XOR swizzle
    __shared__ short Vts[64 * 64];   // [dim][key], 8-chunk XOR swizzle
    __shared__ short Ps[64 * 64];    // [qrow][key], 8-chunk XOR swizzle (wave-private rows)
    short8 aq[4];
    const short* qbase = (const short*)q_bf + ((size_t)bh * SEQ + qt * 64 + w * 16 + lm) * 128;
    #pragma unroll
    for (int st = 0; st < 4; st++) aq[st] = *(const short8*)(qbase + st * 32 + g * 8);
    f32x4 oacc[4] = {};
    float mrow[4], lrow[4];
    #pragma unroll
    for (int r = 0; r < 4; r++) { mrow[r] = -1e30f; lrow[r] = 0.f; }
    const short* kb = (const short*)k_bf + (size_t)bh * SEQ * 128;
    const short* vb = (const short*)vt_bf + (size_t)bh * 64 * SEQ;

    for (int kt = 0; kt <= qt; kt++) {
        __syncthreads();   // prior PV reads done before restage
        #pragma unroll
        for (int it = 0; it < 4; it++) {
            int cid = tid + it * 256;
            int row = cid >> 4, p = cid & 15;
            int c = p ^ (row & 15);
            *(short8*)(&Ks[row * 128 + p * 8]) = *(const short8*)(kb + (size_t)(kt * 64 + row) * 128 + c * 8);
        }
        #pragma unroll
        for (int it = 0; it < 2; it++) {
            int cid = tid + it * 256;
            int row = cid >> 3, p = cid & 7;
            int c = p ^ (row & 7);
            *(short8*)(&Vts[row * 64 + p * 8]) = *(const short8*)(vb + (size_t)row * SEQ + kt * 64 + c * 8);
        }
        __syncthreads();
        // QK^T: s[j] = 16x16 tile (rows=q, cols=keys j*16..)
        f32x4 s[4] = {};
        #pragma unroll
        for (int st = 0; st < 4; st++) {
            #pragma unroll
            for (int j = 0; j < 4; j++) {
                int row = j * 16 + lm;
                int q = (st * 4 + g) ^ (row & 15);
                short8 bk = *(const short8*)(&Ks[row * 128 + q * 8]);
                s[j] = __builtin_amdgcn_mfma_f32_16x16x32_bf16(aq[st], bk, s[j], 0, 0, 0);
            }
        }
        if (kt == qt) {
            #pragma unroll
            for (int j = 0; j < 4; j++)
                #pragma unroll
                for (int r = 0; r < 4; r++)
                    if (j * 16 + lm > w * 16 + g * 4 + r) s[j][r] = -1e30f;
        }
        // online softmax per row r (cols spread over 16 lanes x 4 j-tiles)
        float fac[4];
        #pragma unroll
        for (int r = 0; r < 4; r++) {
            float mx = fmaxf(fmaxf(s[0][r], s[1][r]), fmaxf(s[2][r], s[3][r]));
            mx = fmaxf(mx, __shfl_xor(mx, 1));
            mx = fmaxf(mx, __shfl_xor(mx, 2));
            mx = fmaxf(mx, __shfl_xor(mx, 4));
            mx = fmaxf(mx, __shfl_xor(mx, 8));
            float mnew = fmaxf(mrow[r], mx);
            float ps = 0.f;
            #pragma unroll
            for (int j = 0; j < 4; j++) {
                float pv = __expf(s[j][r] - mnew);
                s[j][r] = pv;
                ps += pv;
            }
            ps += __shfl_xor(ps, 1);
            ps += __shfl_xor(ps, 2);
            ps += __shfl_xor(ps, 4);
            ps += __shfl_xor(ps, 8);
            fac[r] = __expf(mrow[r] - mnew);
            lrow[r] = lrow[r] * fac[r] + ps;
            mrow[r] = mnew;
        }
        #pragma unroll
        for (int j2 = 0; j2 < 4; j2++)
            #pragma unroll
            for (int r = 0; r < 4; r++) oacc[j2][r] *= fac[r];
        // P -> LDS (bf16), wave-private rows
        #pragma unroll
        for (int j = 0; j < 4; j++) {
            #pragma unroll
            for (int r = 0; r < 4; r++) {
                int rowl = w * 16 + g * 4 + r;
                int col = j * 16 + lm;
                int ch = (col >> 3) ^ (rowl & 7);
                Ps[rowl * 64 + ch * 8 + (col & 7)] = f2bf_s(s[j][r]);
            }
        }
        __syncthreads();   // conservative: ensure P visible before frag reads
        // PV: oacc[j2] += P(16x64) @ Vt(j2-dim-tile)
        #pragma unroll
        for (int st = 0; st < 2; st++) {
            int rowp = w * 16 + lm;
            int qp = (st * 4 + g) ^ (rowp & 7);
            short8 ap = *(const short8*)(&Ps[rowp * 64 + qp * 8]);
            #pragma unroll
            for (int j2 = 0; j2 < 4; j2++) {
                int rowv = j2 * 16 + lm;
                int qv = (st * 4 + g) ^ (rowv & 7);
                short8 bv = *(const short8*)(&Vts[rowv * 64 + qv * 8]);
                oacc[j2] = __builtin_amdgcn_mfma_f32_16x16x32_bf16(ap, bv, oacc[j2], 0, 0, 0);
            }
        }
    }
    #pragma unroll
    for (int r = 0; r < 4; r++) {
        float inv = 1.f / lrow[r];
        size_t rowg = (size_t)b * SEQ + qt * 64 + w * 16 + g * 4 + r;
        #pragma unroll
        for (int j2 = 0; j2 < 4; j2++)
            obuf[rowg * HDIM + h * 64 + j2 * 16 + lm] = __float2bfloat16(oacc[j2][r] * inv);
    }
}

// ---------------- zero small int scratch ----------------
__global__ void init_kernel(int* counts, int* pos) {
    int t = threadIdx.x;
    if (t < NEXP) { counts[t] = 0; pos[t] = 0; }
}

// ---------------- Routing: one wave per row ----------------
__global__ __launch_bounds__(64) void route_kernel(const float* __restrict__ xf,
                                                   const float* __restrict__ cent,
                                                   const float* __restrict__ rbias,
                                                   int* __restrict__ route_i,
                                                   float* __restrict__ route_w,
                                                   int* __restrict__ counts) {
    int row = blockIdx.x;
    int lane = threadIdx.x;
    const float* xr = xf + (size_t)row * HDIM;
    float p[NEXP] = {};
    for (int j = lane; j < HDIM; j += 64) {
        float xv = xr[j];
        for (int e = 0; e < NEXP; e++) p[e] += xv * cent[e * HDIM + j];
    }
    for (int e = 0; e < NEXP; e++) {
        float v = p[e];
        for (int o = 32; o > 0; o >>= 1) v += __shfl_down(v, o);
        p[e] = v;
    }
    if (lane == 0) {
        float biased[NEXP];
        for (int e = 0; e < NEXP; e++) {
            float aff = 1.f / (1.f + expf(-p[e]));
            biased[e] = aff + rbias[e];
        }
        int i0 = 0; float v0 = biased[0];
        for (int e = 1; e < NEXP; e++) if (biased[e] > v0) { v0 = biased[e]; i0 = e; }
        int i1 = -1; float v1 = -1e30f;
        for (int e = 0; e < NEXP; e++) if (e != i0 && biased[e] > v1) { v1 = biased[e]; i1 = e; }
        float e1 = expf(v1 - v0);
        float wsum = 1.f + e1;
        route_i[row * 2] = i0; route_i[row * 2 + 1] = i1;
        route_w[row * 2] = 1.f / wsum; route_w[row * 2 + 1] = e1 / wsum;
        atomicAdd(&counts[i0], 1);
        atomicAdd(&counts[i1], 1);
    }
}

__global__ void offsets_kernel(const int* counts, int* eoff, float* out_counts) {
    int acc = 0;
    for (int e = 0; e < NEXP; e++) { eoff[e] = acc; acc += counts[e]; out_counts[e] = (float)counts[e]; }
    eoff[NEXP] = acc;
}

__global__ void scatter_kernel(const int* route_i, const float* route_w, const int* eoff,
                               int* pos, int* tok_id, float* tok_w) {
    int row = blockIdx.x * 256 + threadIdx.x;
    if (row >= ROWS) return;
    for (int sl = 0; sl < 2; sl++) {
        int e = route_i[row * 2 + sl];
        int p = atomicAdd(&pos[e], 1);
        int dst = eoff[e] + p;
        tok_id[dst] = row;
        tok_w[dst] = route_w[row * 2 + sl];
    }
}

// ---------------- MoE gate/up, bf16 MFMA (proven r4) ----------------
__global__ __launch_bounds__(256) void moe_gu_mfma(const __hip_bfloat16* __restrict__ xf_bf,
                                                   const __hip_bfloat16* __restrict__ Wg_t,
                                                   const __hip_bfloat16* __restrict__ Wu_t,
                                                   const int* __restrict__ counts,
                                                   const int* __restrict__ eoff,
                                                   const int* __restrict__ tok_id,
                                                   __hip_bfloat16* __restrict__ hh) {
    int e = blockIdx.z;
    int n_e = counts[e];
    int t0 = blockIdx.y * 128;
    if (t0 >= n_e) return;
    int n0 = blockIdx.x * 64;
    __shared__ short As[128 * 64];
    __shared__ short Bgs[64 * 64];
    __shared__ short Bus[64 * 64];
    __shared__ int toks[128];
    int tid = threadIdx.x;
    int lane = tid & 63, w = tid >> 6;
    int wr = w >> 1, wc = w & 1;
    if (tid < 128) {
        int idx = t0 + tid;
        toks[tid] = (idx < n_e) ? tok_id[eoff[e] + idx] : 0;
    }
    __syncthreads();
    f32x4 accg[4][2] = {};
    f32x4 accu[4][2] = {};
    const __hip_bfloat16* Wge = Wg_t + (size_t)e * DFF * HDIM;
    const __hip_bfloat16* Wue = Wu_t + (size_t)e * DFF * HDIM;
    for (int k0 = 0; k0 < HDIM; k0 += 64) {
        #pragma unroll
        for (int rr = 0; rr < 4; rr++) {
            int chunk = tid + rr * 256;
            int row = chunk >> 3, p = chunk & 7;
            int c = p ^ (row & 7);
            *(short8*)(&As[chunk * 8]) =
                *(const short8*)((const short*)xf_bf + (size_t)toks[row] * HDIM + k0 + c * 8);
        }
        #pragma unroll
        for (int rr = 0; rr < 2; rr++) {
            int chunk = tid + rr * 256;
            int row = chunk >> 3, p = chunk & 7;
            int c = p ^ (row & 7);
            *(short8*)(&Bgs[chunk * 8]) =
                *(const short8*)((const short*)Wge + (size_t)(n0 + row) * HDIM + k0 + c * 8);
            *(short8*)(&Bus[chunk * 8]) =
                *(const short8*)((const short*)Wue + (size_t)(n0 + row) * HDIM + k0 + c * 8);
        }
        __syncthreads();
        #pragma unroll
        for (int kk = 0; kk < 2; kk++) {
            short8 a[4], bg[2], bu[2];
            #pragma unroll
            for (int i = 0; i < 4; i++) {
                int row = wr * 64 + i * 16 + (lane & 15);
                int c = (kk * 4 + (lane >> 4)) ^ (row & 7);
                a[i] = *(const short8*)(&As[row * 64 + c * 8]);
            }
            #pragma unroll
            for (int j = 0; j < 2; j++) {
                int row = wc * 32 + j * 16 + (lane & 15);
                int c = (kk * 4 + (lane >> 4)) ^ (row & 7);
                bg[j] = *(const short8*)(&Bgs[row * 64 + c * 8]);
                bu[j] = *(const short8*)(&Bus[row * 64 + c * 8]);
            }
            #pragma unroll
            for (int i = 0; i < 4; i++)
                #pragma unroll
                for (int j = 0; j < 2; j++) {
                    accg[i][j] = __builtin_amdgcn_mfma_f32_16x16x32_bf16(a[i], bg[j], accg[i][j], 0, 0, 0);
                    accu[i][j] = __builtin_amdgcn_mfma_f32_16x16x32_bf16(a[i], bu[j], accu[i][j], 0, 0, 0);
                }
        }
        __syncthreads();
    }
    #pragma unroll
    for (int i = 0; i < 4; i++) {
        #pragma unroll
        for (int r = 0; r < 4; r++) {
            int row = wr * 64 + i * 16 + (lane >> 4) * 4 + r;
            if (t0 + row < n_e) {
                size_t slot = (size_t)eoff[e] + t0 + row;
                #pragma unroll
                for (int j = 0; j < 2; j++) {
                    float gv = accg[i][j][r];
                    float uv = accu[i][j][r];
                    float val = gv / (1.f + __expf(-gv)) * uv;
                    hh[slot * DFF + n0 + wc * 32 + j * 16 + (lane & 15)] = __float2bfloat16(val);
                }
            }
        }
    }
}

// ---------------- MoE down, bf16 MFMA (proven r4) ----------------
__global__ __launch_bounds__(256) void moe_down_mfma(const __hip_bfloat16* __restrict__ hh,
                                                     const __hip_bfloat16* __restrict__ Wd_t,
                                                     const int* __restrict__ counts,
                                                     const int* __restrict__ eoff,
                                                     const int* __restrict__ tok_id,
                                                     const float* __restrict__ tok_w,
                                                     float* __restrict__ out) {
    int e = blockIdx.z;
    int n_e = counts[e];
    int t0 = blockIdx.y * 128;
    if (t0 >= n_e) return;
    int n0 = blockIdx.x * 128;
    __shared__ short As[128 * 64];
    __shared__ short Bs[128 * 64];
    int tid = threadIdx.x;
    int lane = tid & 63, w = tid >> 6;
    int wr = w >> 1, wc = w & 1;
    f32x4 acc[4][4] = {};
    const __hip_bfloat16* Ae = hh + (size_t)(eoff[e] + t0) * DFF;
    const __hip_bfloat16* Be = Wd_t + (size_t)e * HDIM * DFF;
    for (int k0 = 0; k0 < DFF; k0 += 64) {
        #pragma unroll
        for (int rr = 0; rr < 4; rr++) {
            int chunk = tid + rr * 256;
            int row = chunk >> 3, p = chunk & 7;
            int c = p ^ (row & 7);
            *(short8*)(&As[chunk * 8]) =
                *(const short8*)((const short*)Ae + (size_t)row * DFF + k0 + c * 8);
            *(short8*)(&Bs[chunk * 8]) =
                *(const short8*)((const short*)Be + (size_t)(n0 + row) * DFF + k0 + c * 8);
        }
        __syncthreads();
        #pragma unroll
        for (int kk = 0; kk < 2; kk++) {
            short8 a[4], bv[4];
            #pragma unroll
            for (int i = 0; i < 4; i++) {
                int row = wr * 64 + i * 16 + (lane & 15);
                int c = (kk * 4 + (lane >> 4)) ^ (row & 7);
                a[i] = *(const short8*)(&As[row * 64 + c * 8]);
            }
            #pragma unroll
            for (int j = 0; j < 4; j++) {
                int row = wc * 64 + j * 16 + (lane & 15);
                int c = (kk * 4 + (lane >> 4)) ^ (row & 7);
                bv[j] = *(const short8*)(&Bs[row * 64 + c * 8]);
            }
            #pragma unroll
            for (int i = 0; i < 4; i++)
                #pragma unroll
                for (int j = 0; j < 4; j++)
                    acc[i][j] = __builtin_amdgcn_mfma_f32_16x16x32_bf16(a[i], bv[j], acc[i][j], 0, 0, 0);
        }
        __syncthreads();
    }
    #pragma unroll
    for (int i = 0; i < 4; i++) {
        #pragma unroll
        for (int r = 0; r < 4; r++) {
            int row = wr * 64 + i * 16 + (lane >> 4) * 4 + r;
            if (t0 + row < n_e) {
                int slot = eoff[e] + t0 + row;
                int tok = tok_id[slot];
                float tw = tok_w[slot];
                #pragma unroll
                for (int j = 0; j < 4; j++) {
                    int col = n0 + wc * 64 + j * 16 + (lane & 15);
                    atomicAdd(&out[(size_t)tok * HDIM + col], tw * acc[i][j][r]);
                }
            }
        }
    }
}

extern "C" void kernel_launch(void* const* d_in, const int* in_sizes, int n_in,
                              void* d_out, int out_size, void* d_ws, size_t ws_size,
                              hipStream_t stream) {
    const float* x = (const float*)d_in[0];
    const float* ln1_g = (const float*)d_in[1];
    const float* ln1_b = (const float*)d_in[2];
    const float* W_ckv = (const float*)d_in[3];
    const float* W_kv = (const float*)d_in[4];
    const float* W_cq = (const float*)d_in[5];
    const float* W_q = (const float*)d_in[6];
    const float* W_qr = (const float*)d_in[7];
    const float* W_kr = (const float*)d_in[8];
    const float* W_o = (const float*)d_in[9];
    const float* ln2_g = (const float*)d_in[10];
    const float* ln2_b = (const float*)d_in[11];
    const float* cent = (const float*)d_in[12];
    const float* rbias = (const float*)d_in[13];
    const float* Wg = (const float*)d_in[14];
    const float* Wu = (const float*)d_in[15];
    const float* Wd = (const float*)d_in[16];
    float* out = (float*)d_out;

    float* ws = (float*)d_ws;
    // ---- Region A (bf16 attention pipeline; later overwritten by MoE weight alias) ----
    __hip_bfloat16* h1_bf   = (__hip_bfloat16*)ws;                    // 4096x1024
    __hip_bfloat16* c_kv_bf = h1_bf + (size_t)ROWS * HDIM;            // 4096x256
    __hip_bfloat16* c_q_bf  = c_kv_bf + (size_t)ROWS * LDIM;
    __hip_bfloat16* k_r_bf  = c_q_bf + (size_t)ROWS * LDIM;           // 4096x64
    __hip_bfloat16* q_bf    = k_r_bf + (size_t)ROWS * RDIM;           // [bh,s,128] 8.39M
    __hip_bfloat16* k_bf    = q_bf + (size_t)ROWS * 2048;
    __hip_bfloat16* v_bf    = k_bf + (size_t)ROWS * 2048;             // 4096x1024
    __hip_bfloat16* vt_bf   = v_bf + (size_t)ROWS * HDIM;             // [bh,64,s]
    __hip_bfloat16* obuf_bf = vt_bf + (size_t)ROWS * HDIM;
    __hip_bfloat16* Wckv_t  = obuf_bf + (size_t)ROWS * HDIM;          // [256][1024]
    __hip_bfloat16* Wcq_t   = Wckv_t + 1024 * 256;
    __hip_bfloat16* Wkv_t   = Wcq_t + 1024 * 256;                     // [2048][256]
    __hip_bfloat16* Wq_t    = Wkv_t + 2048 * 256;                     // [1024][256]
    __hip_bfloat16* Wqr_t   = Wq_t + 1024 * 256;
    __hip_bfloat16* Wo_t    = Wqr_t + 1024 * 256;                     // [1024][1024]
    __hip_bfloat16* Wkr_t   = Wo_t + 1024 * 1024;                     // [64][256]
    // region A total 38.57M shorts = 19.28M floats < 25.17M alias floor
    // ---- MoE alias (from ws base, written after attention phase is dead) ----
    __hip_bfloat16* Wg_t  = (__hip_bfloat16*)ws;                      // 8x2048x1024 each
    __hip_bfloat16* Wu_t  = Wg_t + (size_t)NEXP * DFF * HDIM;
    __hip_bfloat16* Wd_t  = Wu_t + (size_t)NEXP * DFF * HDIM;
    __hip_bfloat16* xf_bf = Wd_t + (size_t)NEXP * DFF * HDIM;         // 4096x1024
    float* xf = ws + ((size_t)3 * NEXP * DFF * HDIM + (size_t)ROWS * HDIM) / 2;  // 27,262,976 floats in
    __hip_bfloat16* hh = (__hip_bfloat16*)xf;                         // aliases xf (dead after routing)
    float* tail = xf + (size_t)(2 * ROWS + 128) * DFF / 2;
    float* route_w = tail;
    float* tok_w = tail + ROWS * 2;
    int* ibuf = (int*)(tok_w + ROWS * 2);
    int* route_i = ibuf;           // 8192
    int* counts = ibuf + 8192;     // 8
    int* eoff = ibuf + 8200;       // 9
    int* pos = ibuf + 8212;        // 8
    int* tok_id = ibuf + 8224;     // 8192

    // 1. LN1 -> bf16
    ln_kernel<<<ROWS, 256, 0, stream>>>(x, ln1_g, ln1_b, nullptr, h1_bf);
    // 2. small weight transposes (bf16 [N][K]); 0.125 attn scale folded into W_q/W_qr
    transpose_bf16_kernel<<<dim3(4, 16, 1), 256, 0, stream>>>(W_ckv, Wckv_t, 1024, 256, 1.f);
    transpose_bf16_kernel<<<dim3(4, 16, 1), 256, 0, stream>>>(W_cq, Wcq_t, 1024, 256, 1.f);
    transpose_bf16_kernel<<<dim3(32, 4, 1), 256, 0, stream>>>(W_kv, Wkv_t, 256, 2048, 1.f);
    transpose_bf16_kernel<<<dim3(16, 4, 1), 256, 0, stream>>>(W_q, Wq_t, 256, 1024, 0.125f);
    transpose_bf16_kernel<<<dim3(16, 4, 1), 256, 0, stream>>>(W_qr, Wqr_t, 256, 1024, 0.125f);
    transpose_bf16_kernel<<<dim3(16, 16, 1), 256, 0, stream>>>(W_o, Wo_t, 1024, 1024, 1.f);
    transpose_bf16_kernel<<<dim3(1, 4, 1), 256, 0, stream>>>(W_kr, Wkr_t, 256, 64, 1.f);
    // 3-8. projections (bf16 MFMA)
    gemm_bf16_kernel<<<dim3(2, 32), 256, 0, stream>>>(h1_bf, Wckv_t, nullptr, c_kv_bf, nullptr, ROWS, 256, 1024, 0);
    gemm_bf16_kernel<<<dim3(2, 32), 256, 0, stream>>>(h1_bf, Wcq_t, nullptr, c_q_bf, nullptr, ROWS, 256, 1024, 0);
    gemm_bf16_kernel<<<dim3(8, 32), 256, 0, stream>>>(c_kv_bf, Wkv_t, nullptr, k_bf, nullptr, ROWS, 1024, 256, 1);            // k_c packed
    gemm_bf16_kernel<<<dim3(8, 32), 256, 0, stream>>>(c_kv_bf, Wkv_t + 1024 * 256, nullptr, v_bf, nullptr, ROWS, 1024, 256, 0); // v row-major
    gemm_bf16_kernel<<<dim3(8, 32), 256, 0, stream>>>(c_q_bf, Wq_t, nullptr, q_bf, nullptr, ROWS, 1024, 256, 1);              // q_c packed (scaled)
    gemm_bf16_kernel<<<dim3(8, 32), 256, 0, stream>>>(c_q_bf, Wqr_t, nullptr, q_bf, nullptr, ROWS, 1024, 256, 2);             // q_r packed HI (scaled)
    gemm_kr_kernel<<<64, 256, 0, stream>>>(c_kv_bf, Wkr_t, k_r_bf);
    // 9. RoPE + packing
    rope_q_kernel<<<(4 * 16 * 1024 * 32) / 256, 256, 0, stream>>>(q_bf);
    rope_pack_kr_kernel<<<(ROWS * 32) / 256, 256, 0, stream>>>(k_r_bf, k_bf);
    pack_vt_kernel<<<dim3(16, 16, 4), 256, 0, stream>>>(v_bf, vt_bf);
    // 10. MFMA flash attention
    attn_mfma_kernel<<<dim3(SEQ / 64, NHEAD, 4), 256, 0, stream>>>(q_bf, k_bf, vt_bf, obuf_bf);
    // 11. out = obuf @ W_o + x
    gemm_bf16_kernel<<<dim3(8, 32), 256, 0, stream>>>(obuf_bf, Wo_t, out, nullptr, x, ROWS, 1024, 1024, 0);
    // 12. LN2 -> xf (fp32)
    ln_kernel<<<ROWS, 256, 0, stream>>>(out, ln2_g, ln2_b, xf, nullptr);
    // 13. MoE weight transposes (overwrite region A) + xf cvt
    transpose_bf16_kernel<<<dim3(32, 16, NEXP), 256, 0, stream>>>(Wg, Wg_t, HDIM, DFF, 1.f);
    transpose_bf16_kernel<<<dim3(32, 16, NEXP), 256, 0, stream>>>(Wu, Wu_t, HDIM, DFF, 1.f);
    transpose_bf16_kernel<<<dim3(16, 32, NEXP), 256, 0, stream>>>(Wd, Wd_t, DFF, HDIM, 1.f);
    cvt_bf16_kernel<<<(ROWS * HDIM / 4) / 256, 256, 0, stream>>>(xf, xf_bf);
    // 14. routing (reads fp32 xf; hh overwrites xf only afterwards)
    init_kernel<<<1, 64, 0, stream>>>(counts, pos);
    route_kernel<<<ROWS, 64, 0, stream>>>(xf, cent, rbias, route_i, route_w, counts);
    offsets_kernel<<<1, 1, 0, stream>>>(counts, eoff, out + (size_t)ROWS * HDIM);
    scatter_kernel<<<ROWS / 256, 256, 0, stream>>>(route_i, route_w, eoff, pos, tok_id, tok_w);
    // 15. MoE
    moe_gu_mfma<<<dim3(DFF / 64, 32, NEXP), 256, 0, stream>>>(xf_bf, Wg_t, Wu_t, counts, eoff, tok_id, hh);
    moe_down_mfma<<<dim3(HDIM / 128, 32, NEXP), 256, 0, stream>>>(hh, Wd_t, counts, eoff, tok_id, tok_w, out);
}

// Round 6
// 887.487 us; speedup vs baseline: 6.5923x; 1.0349x over previous
//
#include <hip/hip_runtime.h>
#include <hip/hip_bf16.h>
#include <math.h>

#define SEQ 1024
#define HDIM 1024
#define NHEAD 16
#define HEADD 64
#define LDIM 256
#define RDIM 64
#define DFF 2048
#define NEXP 8
#define ROWS 4096  // B*S

typedef __attribute__((ext_vector_type(8))) short short8;
typedef __attribute__((ext_vector_type(4))) float f32x4;

static __device__ __forceinline__ short f2bf_s(float v) {
    __hip_bfloat16 hb = __float2bfloat16(v);
    return *reinterpret_cast<short*>(&hb);
}

// async global->LDS, 16B per lane; dest is wave-uniform base + lane*16
static __device__ __forceinline__ void gload_lds16(const void* g, void* l) {
    __builtin_amdgcn_global_load_lds(
        (const __attribute__((address_space(1))) unsigned int*)g,
        (__attribute__((address_space(3))) unsigned int*)l,
        16, 0, 0);
}

// ---------------- LayerNorm (fp32 in, fp32 and/or bf16 out) ----------------
__global__ __launch_bounds__(256) void ln_kernel(const float* __restrict__ x,
                                                 const float* __restrict__ g,
                                                 const float* __restrict__ b,
                                                 float* __restrict__ out_f,
                                                 __hip_bfloat16* __restrict__ out_bf) {
    int row = blockIdx.x;
    int tid = threadIdx.x;
    __shared__ float red[256];
    __shared__ float red2[256];
    const float* xr = x + (size_t)row * HDIM;
    float s = 0.f, s2 = 0.f;
    for (int j = tid; j < HDIM; j += 256) { float v = xr[j]; s += v; s2 += v * v; }
    red[tid] = s; red2[tid] = s2; __syncthreads();
    for (int o = 128; o > 0; o >>= 1) {
        if (tid < o) { red[tid] += red[tid + o]; red2[tid] += red2[tid + o]; }
        __syncthreads();
    }
    float mean = red[0] * (1.f / HDIM);
    float var = red2[0] * (1.f / HDIM) - mean * mean;
    float inv = rsqrtf(var + 1e-5f);
    for (int j = tid; j < HDIM; j += 256) {
        float v = (xr[j] - mean) * inv * g[j] + b[j];
        if (out_f) out_f[(size_t)row * HDIM + j] = v;
        if (out_bf) out_bf[(size_t)row * HDIM + j] = __float2bfloat16(v);
    }
}

// ---------------- weight transpose+convert: fp32 [K][N] -> bf16 [N][K] (x scale) ----------------
__global__ __launch_bounds__(256) void transpose_bf16_kernel(const float* __restrict__ src,
                                                             __hip_bfloat16* __restrict__ dst,
                                                             int K, int N, float scale) {
    int n0 = blockIdx.x * 64, k0 = blockIdx.y * 64;
    size_t eo = (size_t)blockIdx.z * K * N;
    src += eo; dst += eo;
    __shared__ float t[64][65];
    int tid = threadIdx.x;
    #pragma unroll
    for (int i = 0; i < 16; i++) {
        int id = tid + i * 256;
        int r = id >> 6, cn = id & 63;
        t[r][cn] = src[(size_t)(k0 + r) * N + n0 + cn];
    }
    __syncthreads();
    #pragma unroll
    for (int i = 0; i < 16; i++) {
        int id = tid + i * 256;
        int rn = id >> 6, ck = id & 63;
        dst[(size_t)(n0 + rn) * K + k0 + ck] = __float2bfloat16(t[ck][rn] * scale);
    }
}

// ---------------- generic bf16 MFMA GEMM ----------------
// C[M][N] = A[M][K] @ Bt[N][K]^T. grid (N/128, M/128), 256 thr = 4 waves (2x2), wave=64x64.
// mode 0: row-major, write Cf (+R) and/or Cbf. mode 1: PACK_LO (bf16 [b,h,s,128] d=0..63).
// mode 2: PACK_HI (d=64..127).
__global__ __launch_bounds__(256) void gemm_bf16_kernel(const __hip_bfloat16* __restrict__ A,
                                                        const __hip_bfloat16* __restrict__ Bt,
                                                        float* __restrict__ Cf,
                                                        __hip_bfloat16* __restrict__ Cbf,
                                                        const float* __restrict__ R,
                                                        int M, int N, int K, int mode) {
    int m0 = blockIdx.y * 128, n0 = blockIdx.x * 128;
    __shared__ short As[128 * 64];
    __shared__ short Bs[128 * 64];
    int tid = threadIdx.x;
    int lane = tid & 63, w = tid >> 6;
    int wr = w >> 1, wc = w & 1;
    int lm = lane & 15, g = lane >> 4;
    f32x4 acc[4][4] = {};
    for (int k0 = 0; k0 < K; k0 += 64) {
        #pragma unroll
        for (int rr = 0; rr < 4; rr++) {
            int sb = w * 64 + rr * 256;          // wave-uniform slot base
            int slot = sb + lane;
            int row = slot >> 3, p = slot & 7;
            int c = p ^ (row & 7);
            gload_lds16((const short*)A + (size_t)(m0 + row) * K + k0 + c * 8, &As[sb * 8]);
            gload_lds16((const short*)Bt + (size_t)(n0 + row) * K + k0 + c * 8, &Bs[sb * 8]);
        }
        __syncthreads();
        #pragma unroll
        for (int kk = 0; kk < 2; kk++) {
            short8 a[4], bv[4];
            #pragma unroll
            for (int i = 0; i < 4; i++) {
                int row = wr * 64 + i * 16 + lm;
                int c = (kk * 4 + g) ^ (row & 7);
                a[i] = *(const short8*)(&As[row * 64 + c * 8]);
            }
            #pragma unroll
            for (int j = 0; j < 4; j++) {
                int row = wc * 64 + j * 16 + lm;
                int c = (kk * 4 + g) ^ (row & 7);
                bv[j] = *(const short8*)(&Bs[row * 64 + c * 8]);
            }
            #pragma unroll
            for (int i = 0; i < 4; i++)
                #pragma unroll
                for (int j = 0; j < 4; j++)
                    acc[i][j] = __builtin_amdgcn_mfma_f32_16x16x32_bf16(a[i], bv[j], acc[i][j], 0, 0, 0);
        }
        __syncthreads();
    }
    #pragma unroll
    for (int i = 0; i < 4; i++) {
        #pragma unroll
        for (int r = 0; r < 4; r++) {
            int m = m0 + wr * 64 + i * 16 + g * 4 + r;
            #pragma unroll
            for (int j = 0; j < 4; j++) {
                int n = n0 + wc * 64 + j * 16 + lm;
                float v = acc[i][j][r];
                if (mode == 0) {
                    size_t idx = (size_t)m * N + n;
                    if (R) v += R[idx];
                    if (Cf) Cf[idx] = v;
                    if (Cbf) Cbf[idx] = __float2bfloat16(v);
                } else {
                    size_t idx = ((size_t)((m >> 10) * 16 + (n >> 6)) * SEQ + (m & 1023)) * 128
                               + (n & 63) + (mode == 2 ? 64 : 0);
                    Cbf[idx] = __float2bfloat16(v);
                }
            }
        }
    }
}

// ---------------- tiny k_r GEMM: [4096][256] @ [64][256]^T -> bf16 [4096][64] ----------------
__global__ __launch_bounds__(256) void gemm_kr_kernel(const __hip_bfloat16* __restrict__ A,
                                                      const __hip_bfloat16* __restrict__ Bt,
                                                      __hip_bfloat16* __restrict__ C) {
    int m0 = blockIdx.x * 64;
    int tid = threadIdx.x;
    int lane = tid & 63, w = tid >> 6;
    int lm = lane & 15, g = lane >> 4;
    f32x4 acc[4] = {};
    const short* Ab = (const short*)A + (size_t)(m0 + w * 16 + lm) * 256;
    #pragma unroll
    for (int ks = 0; ks < 8; ks++) {
        short8 a = *(const short8*)(Ab + ks * 32 + g * 8);
        #pragma unroll
        for (int j = 0; j < 4; j++) {
            short8 b = *(const short8*)((const short*)Bt + (size_t)(j * 16 + lm) * 256 + ks * 32 + g * 8);
            acc[j] = __builtin_amdgcn_mfma_f32_16x16x32_bf16(a, b, acc[j], 0, 0, 0);
        }
    }
    #pragma unroll
    for (int r = 0; r < 4; r++)
        #pragma unroll
        for (int j = 0; j < 4; j++)
            C[(size_t)(m0 + w * 16 + g * 4 + r) * 64 + j * 16 + lm] = __float2bfloat16(acc[j][r]);
}

// ---------------- RoPE on packed q_bf HI half (in place, bf16) ----------------
__global__ void rope_q_kernel(__hip_bfloat16* __restrict__ q_bf) {
    int idx = blockIdx.x * 256 + threadIdx.x;   // [bh(6b)|s(10b)|i(5b)]
    int i = idx & 31;
    int s = (idx >> 5) & 1023;
    int bh = idx >> 15;
    float freq = __expf(-9.210340372f * (float)i / 32.f);
    float fr = (float)s * freq;
    float sn, cs;
    __sincosf(fr, &sn, &cs);
    __hip_bfloat16* p = q_bf + ((size_t)bh * SEQ + s) * 128 + 64 + 2 * i;
    float xe = __bfloat162float(p[0]), xo = __bfloat162float(p[1]);
    p[0] = __float2bfloat16(xe * cs - xo * sn);
    p[1] = __float2bfloat16(xe * sn + xo * cs);
}

// ---------------- RoPE k_r + broadcast-pack into k_bf HI ----------------
__global__ void rope_pack_kr_kernel(const __hip_bfloat16* __restrict__ k_r_bf,
                                    __hip_bfloat16* __restrict__ k_bf) {
    int idx = blockIdx.x * 256 + threadIdx.x;   // [row(12b)|i(5b)]
    int i = idx & 31;
    int row = idx >> 5;          // b*SEQ + s
    int s = row & 1023, b = row >> 10;
    float freq = __expf(-9.210340372f * (float)i / 32.f);
    float fr = (float)s * freq;
    float sn, cs;
    __sincosf(fr, &sn, &cs);
    float xe = __bfloat162float(k_r_bf[(size_t)row * 64 + 2 * i]);
    float xo = __bfloat162float(k_r_bf[(size_t)row * 64 + 2 * i + 1]);
    __hip_bfloat16 re = __float2bfloat16(xe * cs - xo * sn);
    __hip_bfloat16 ro = __float2bfloat16(xe * sn + xo * cs);
    #pragma unroll
    for (int h = 0; h < NHEAD; h++) {
        size_t base = ((size_t)(b * 16 + h) * SEQ + s) * 128 + 64 + 2 * i;
        k_bf[base] = re;
        k_bf[base + 1] = ro;
    }
}

// ---------------- V transpose: v_bf [b*s][h*64+d] -> vt_bf [b,h,d,s] ----------------
__global__ __launch_bounds__(256) void pack_vt_kernel(const __hip_bfloat16* __restrict__ v_bf,
                                                      __hip_bfloat16* __restrict__ vt_bf) {
    int s0 = blockIdx.x * 64, h = blockIdx.y, b = blockIdx.z;
    __shared__ short t[64][72];
    int tid = threadIdx.x;
    #pragma unroll
    for (int i = 0; i < 16; i++) {
        int id = tid + i * 256;
        int r = id >> 6, d = id & 63;
        t[r][d] = ((const short*)v_bf)[(size_t)(b * SEQ + s0 + r) * HDIM + h * 64 + d];
    }
    __syncthreads();
    #pragma unroll
    for (int i = 0; i < 16; i++) {
        int id = tid + i * 256;
        int d = id >> 6, cs = id & 63;
        ((short*)vt_bf)[((size_t)(b * 16 + h) * 64 + d) * SEQ + s0 + cs] = t[cs][d];
    }
}

// ---------------- MFMA flash attention ----------------
// grid (SEQ/64, NHEAD, B), 256 thr = 4 waves; wave w owns q-rows [qt*64+w*16, +16).
__global__ __launch_bounds__(256) void attn_mfma_kernel(const __hip_bfloat16* __restrict__ q_bf,
                                                        const __hip_bfloat16* __restrict__ k_bf,
                                                        const __hip_bfloat16* __restrict__ vt_bf,
                                                        __hip_bfloat16* __restrict__ obuf) {
    int qt = blockIdx.x, h = blockIdx.y, b = blockIdx.z;
    int bh = b * NHEAD + h;
    int tid = threadIdx.x;
    int lane = tid & 63, w = tid >> 6;
    int lm = lane & 15, g = lane >> 4;
    __shared__ short Ks[64 * 128];   // [key][d], 16-chunk XOR swizzle
    __shared__ short Vts[64 * 64];   // [dim][key], 8-chunk XOR swizzle
    __shared__ short Ps[64 * 64];    // [qrow][key], 8-chunk XOR swizzle (wave-private rows)
    short8 aq[4];
    const short* qbase = (const short*)q_bf + ((size_t)bh * SEQ + qt * 64 + w * 16 + lm) * 128;
    #pragma unroll
    for (int st = 0; st < 4; st++) aq[st] = *(const short8*)(qbase + st * 32 + g * 8);
    f32x4 oacc[4] = {};
    float mrow[4], lrow[4];
    #pragma unroll
    for (int r = 0; r < 4; r++) { mrow[r] = -1e30f; lrow[r] = 0.f; }
    const short* kb = (const short*)k_bf + (size_t)bh * SEQ * 128;
    const short* vb = (const short*)vt_bf + (size_t)bh * 64 * SEQ;

    for (int kt = 0; kt <= qt; kt++) {
        __syncthreads();   // prior PV reads done before restage
        #pragma unroll
        for (int it = 0; it < 4; it++) {
            int sb = w * 64 + it * 256;
            int cid = sb + lane;
            int row = cid >> 4, p = cid & 15;
            int c = p ^ (row & 15);
            gload_lds16(kb + (size_t)(kt * 64 + row) * 128 + c * 8, &Ks[sb * 8]);
        }
        #pragma unroll
        for (int it = 0; it < 2; it++) {
            int sb = w * 64 + it * 256;
            int cid = sb + lane;
            int row = cid >> 3, p = cid & 7;
            int c = p ^ (row & 7);
            gload_lds16(vb + (size_t)row * SEQ + kt * 64 + c * 8, &Vts[sb * 8]);
        }
        __syncthreads();
        // QK^T
        f32x4 s[4] = {};
        #pragma unroll
        for (int st = 0; st < 4; st++) {
            #pragma unroll
            for (int j = 0; j < 4; j++) {
                int row = j * 16 + lm;
                int q = (st * 4 + g) ^ (row & 15);
                short8 bk = *(const short8*)(&Ks[row * 128 + q * 8]);
                s[j] = __builtin_amdgcn_mfma_f32_16x16x32_bf16(aq[st], bk, s[j], 0, 0, 0);
            }
        }
        if (kt == qt) {
            #pragma unroll
            for (int j = 0; j < 4; j++)
                #pragma unroll
                for (int r = 0; r < 4; r++)
                    if (j * 16 + lm > w * 16 + g * 4 + r) s[j][r] = -1e30f;
        }
        // online softmax per row
        float fac[4];
        #pragma unroll
        for (int r = 0; r < 4; r++) {
            float mx = fmaxf(fmaxf(s[0][r], s[1][r]), fmaxf(s[2][r], s[3][r]));
            mx = fmaxf(mx, __shfl_xor(mx, 1));
            mx = fmaxf(mx, __shfl_xor(mx, 2));
            mx = fmaxf(mx, __shfl_xor(mx, 4));
            mx = fmaxf(mx, __shfl_xor(mx, 8));
            float mnew = fmaxf(mrow[r], mx);
            float ps = 0.f;
            #pragma unroll
            for (int j = 0; j < 4; j++) {
                float pv = __expf(s[j][r] - mnew);
                s[j][r] = pv;
                ps += pv;
            }
            ps += __shfl_xor(ps, 1);
            ps += __shfl_xor(ps, 2);
            ps += __shfl_xor(ps, 4);
            ps += __shfl_xor(ps, 8);
            fac[r] = __expf(mrow[r] - mnew);
            lrow[r] = lrow[r] * fac[r] + ps;
            mrow[r] = mnew;
        }
        #pragma unroll
        for (int j2 = 0; j2 < 4; j2++)
            #pragma unroll
            for (int r = 0; r < 4; r++) oacc[j2][r] *= fac[r];
        // P -> LDS (bf16), wave-private rows: no block barrier needed (intra-wave lgkmcnt)
        #pragma unroll
        for (int j = 0; j < 4; j++) {
            #pragma unroll
            for (int r = 0; r < 4; r++) {
                int rowl = w * 16 + g * 4 + r;
                int col = j * 16 + lm;
                int ch = (col >> 3) ^ (rowl & 7);
                Ps[rowl * 64 + ch * 8 + (col & 7)] = f2bf_s(s[j][r]);
            }
        }
        // PV
        #pragma unroll
        for (int st = 0; st < 2; st++) {
            int rowp = w * 16 + lm;
            int qp = (st * 4 + g) ^ (rowp & 7);
            short8 ap = *(const short8*)(&Ps[rowp * 64 + qp * 8]);
            #pragma unroll
            for (int j2 = 0; j2 < 4; j2++) {
                int rowv = j2 * 16 + lm;
                int qv = (st * 4 + g) ^ (rowv & 7);
                short8 bv = *(const short8*)(&Vts[rowv * 64 + qv * 8]);
                oacc[j2] = __builtin_amdgcn_mfma_f32_16x16x32_bf16(ap, bv, oacc[j2], 0, 0, 0);
            }
        }
    }
    #pragma unroll
    for (int r = 0; r < 4; r++) {
        float inv = 1.f / lrow[r];
        size_t rowg = (size_t)b * SEQ + qt * 64 + w * 16 + g * 4 + r;
        #pragma unroll
        for (int j2 = 0; j2 < 4; j2++)
            obuf[rowg * HDIM + h * 64 + j2 * 16 + lm] = __float2bfloat16(oacc[j2][r] * inv);
    }
}

// ---------------- zero small int scratch ----------------
__global__ void init_kernel(int* counts, int* pos) {
    int t = threadIdx.x;
    if (t < NEXP) { counts[t] = 0; pos[t] = 0; }
}

// ---------------- Routing: one wave per row ----------------
__global__ __launch_bounds__(64) void route_kernel(const float* __restrict__ xf,
                                                   const float* __restrict__ cent,
                                                   const float* __restrict__ rbias,
                                                   int* __restrict__ route_i,
                                                   float* __restrict__ route_w,
                                                   int* __restrict__ counts) {
    int row = blockIdx.x;
    int lane = threadIdx.x;
    const float* xr = xf + (size_t)row * HDIM;
    float p[NEXP] = {};
    for (int j = lane; j < HDIM; j += 64) {
        float xv = xr[j];
        for (int e = 0; e < NEXP; e++) p[e] += xv * cent[e * HDIM + j];
    }
    for (int e = 0; e < NEXP; e++) {
        float v = p[e];
        for (int o = 32; o > 0; o >>= 1) v += __shfl_down(v, o);
        p[e] = v;
    }
    if (lane == 0) {
        float biased[NEXP];
        for (int e = 0; e < NEXP; e++) {
            float aff = 1.f / (1.f + expf(-p[e]));
            biased[e] = aff + rbias[e];
        }
        int i0 = 0; float v0 = biased[0];
        for (int e = 1; e < NEXP; e++) if (biased[e] > v0) { v0 = biased[e]; i0 = e; }
        int i1 = -1; float v1 = -1e30f;
        for (int e = 0; e < NEXP; e++) if (e != i0 && biased[e] > v1) { v1 = biased[e]; i1 = e; }
        float e1 = expf(v1 - v0);
        float wsum = 1.f + e1;
        route_i[row * 2] = i0; route_i[row * 2 + 1] = i1;
        route_w[row * 2] = 1.f / wsum; route_w[row * 2 + 1] = e1 / wsum;
        atomicAdd(&counts[i0], 1);
        atomicAdd(&counts[i1], 1);
    }
}

__global__ void offsets_kernel(const int* counts, int* eoff, float* out_counts) {
    int acc = 0;
    for (int e = 0; e < NEXP; e++) { eoff[e] = acc; acc += counts[e]; out_counts[e] = (float)counts[e]; }
    eoff[NEXP] = acc;
}

__global__ void scatter_kernel(const int* route_i, const float* route_w, const int* eoff,
                               int* pos, int* tok_id, float* tok_w) {
    int row = blockIdx.x * 256 + threadIdx.x;
    if (row >= ROWS) return;
    for (int sl = 0; sl < 2; sl++) {
        int e = route_i[row * 2 + sl];
        int p = atomicAdd(&pos[e], 1);
        int dst = eoff[e] + p;
        tok_id[dst] = row;
        tok_w[dst] = route_w[row * 2 + sl];
    }
}

// ---------------- MoE gate/up, bf16 MFMA + global_load_lds staging ----------------
__global__ __launch_bounds__(256) void moe_gu_mfma(const __hip_bfloat16* __restrict__ xf_bf,
                                                   const __hip_bfloat16* __restrict__ Wg_t,
                                                   const __hip_bfloat16* __restrict__ Wu_t,
                                                   const int* __restrict__ counts,
                                                   const int* __restrict__ eoff,
                                                   const int* __restrict__ tok_id,
                                                   __hip_bfloat16* __restrict__ hh) {
    int e = blockIdx.z;
    int n_e = counts[e];
    int t0 = blockIdx.y * 128;
    if (t0 >= n_e) return;
    int n0 = blockIdx.x * 64;
    __shared__ short As[128 * 64];
    __shared__ short Bgs[64 * 64];
    __shared__ short Bus[64 * 64];
    __shared__ int toks[128];
    int tid = threadIdx.x;
    int lane = tid & 63, w = tid >> 6;
    int wr = w >> 1, wc = w & 1;
    if (tid < 128) {
        int idx = t0 + tid;
        toks[tid] = (idx < n_e) ? tok_id[eoff[e] + idx] : 0;
    }
    __syncthreads();
    // per-thread cached A gather bases (static indexing)
    int atok[4], acoff[4];
    #pragma unroll
    for (int rr = 0; rr < 4; rr++) {
        int slot = tid + rr * 256;
        int row = slot >> 3, p = slot & 7;
        atok[rr] = toks[row];
        acoff[rr] = (p ^ (row & 7)) * 8;
    }
    f32x4 accg[4][2] = {};
    f32x4 accu[4][2] = {};
    const __hip_bfloat16* Wge = Wg_t + (size_t)e * DFF * HDIM;
    const __hip_bfloat16* Wue = Wu_t + (size_t)e * DFF * HDIM;
    for (int k0 = 0; k0 < HDIM; k0 += 64) {
        #pragma unroll
        for (int rr = 0; rr < 4; rr++) {
            int sb = w * 64 + rr * 256;
            gload_lds16((const short*)xf_bf + (size_t)atok[rr] * HDIM + k0 + acoff[rr], &As[sb * 8]);
        }
        #pragma unroll
        for (int rr = 0; rr < 2; rr++) {
            int sb = w * 64 + rr * 256;
            int slot = sb + lane;
            int row = slot >> 3, p = slot & 7;
            int c = p ^ (row & 7);
            gload_lds16((const short*)Wge + (size_t)(n0 + row) * HDIM + k0 + c * 8, &Bgs[sb * 8]);
            gload_lds16((const short*)Wue + (size_t)(n0 + row) * HDIM + k0 + c * 8, &Bus[sb * 8]);
        }
        __syncthreads();
        #pragma unroll
        for (int kk = 0; kk < 2; kk++) {
            short8 a[4], bg[2], bu[2];
            #pragma unroll
            for (int i = 0; i < 4; i++) {
                int row = wr * 64 + i * 16 + (lane & 15);
                int c = (kk * 4 + (lane >> 4)) ^ (row & 7);
                a[i] = *(const short8*)(&As[row * 64 + c * 8]);
            }
            #pragma unroll
            for (int j = 0; j < 2; j++) {
                int row = wc * 32 + j * 16 + (lane & 15);
                int c = (kk * 4 + (lane >> 4)) ^ (row & 7);
                bg[j] = *(const short8*)(&Bgs[row * 64 + c * 8]);
                bu[j] = *(const short8*)(&Bus[row * 64 + c * 8]);
            }
            #pragma unroll
            for (int i = 0; i < 4; i++)
                #pragma unroll
                for (int j = 0; j < 2; j++) {
                    accg[i][j] = __builtin_amdgcn_mfma_f32_16x16x32_bf16(a[i], bg[j], accg[i][j], 0, 0, 0);
                    accu[i][j] = __builtin_amdgcn_mfma_f32_16x16x32_bf16(a[i], bu[j], accu[i][j], 0, 0, 0);
                }
        }
        __syncthreads();
    }
    #pragma unroll
    for (int i = 0; i < 4; i++) {
        #pragma unroll
        for (int r = 0; r < 4; r++) {
            int row = wr * 64 + i * 16 + (lane >> 4) * 4 + r;
            if (t0 + row < n_e) {
                size_t slot = (size_t)eoff[e] + t0 + row;
                #pragma unroll
                for (int j = 0; j < 2; j++) {
                    float gv = accg[i][j][r];
                    float uv = accu[i][j][r];
                    float val = gv / (1.f + __expf(-gv)) * uv;
                    hh[slot * DFF + n0 + wc * 32 + j * 16 + (lane & 15)] = __float2bfloat16(val);
                }
            }
        }
    }
}

// ---------------- MoE down, bf16 MFMA + global_load_lds staging ----------------
__global__ __launch_bounds__(256) void moe_down_mfma(const __hip_bfloat16* __restrict__ hh,
                                                     const __hip_bfloat16* __restrict__ Wd_t,
                                                     const int* __restrict__ counts,
                                                     const int* __restrict__ eoff,
                                                     const int* __restrict__ tok_id,
                                                     const float* __restrict__ tok_w,
                                                     float* __restrict__ out) {
    int e = blockIdx.z;
    int n_e = counts[e];
    int t0 = blockIdx.y * 128;
    if (t0 >= n_e) return;
    int n0 = blockIdx.x * 128;
    __shared__ short As[128 * 64];
    __shared__ short Bs[128 * 64];
    int tid = threadIdx.x;
    int lane = tid & 63, w = tid >> 6;
    int wr = w >> 1, wc = w & 1;
    f32x4 acc[4][4] = {};
    const __hip_bfloat16* Ae = hh + (size_t)(eoff[e] + t0) * DFF;
    const __hip_bfloat16* Be = Wd_t + (size_t)e * HDIM * DFF;
    for (int k0 = 0; k0 < DFF; k0 += 64) {
        #pragma unroll
        for (int rr = 0; rr < 4; rr++) {
            int sb = w * 64 + rr * 256;
            int slot = sb + lane;
            int row = slot >> 3, p = slot & 7;
            int c = p ^ (row & 7);
            gload_lds16((const short*)Ae + (size_t)row * DFF + k0 + c * 8, &As[sb * 8]);
            gload_lds16((const short*)Be + (size_t)(n0 + row) * DFF + k0 + c * 8, &Bs[sb * 8]);
        }
        __syncthreads();
        #pragma unroll
        for (int kk = 0; kk < 2; kk++) {
            short8 a[4], bv[4];
            #pragma unroll
            for (int i = 0; i < 4; i++) {
                int row = wr * 64 + i * 16 + (lane & 15);
                int c = (kk * 4 + (lane >> 4)) ^ (row & 7);
                a[i] = *(const short8*)(&As[row * 64 + c * 8]);
            }
            #pragma unroll
            for (int j = 0; j < 4; j++) {
                int row = wc * 64 + j * 16 + (lane & 15);
                int c = (kk * 4 + (lane >> 4)) ^ (row & 7);
                bv[j] = *(const short8*)(&Bs[row * 64 + c * 8]);
            }
            #pragma unroll
            for (int i = 0; i < 4; i++)
                #pragma unroll
                for (int j = 0; j < 4; j++)
                    acc[i][j] = __builtin_amdgcn_mfma_f32_16x16x32_bf16(a[i], bv[j], acc[i][j], 0, 0, 0);
        }
        __syncthreads();
    }
    #pragma unroll
    for (int i = 0; i < 4; i++) {
        #pragma unroll
        for (int r = 0; r < 4; r++) {
            int row = wr * 64 + i * 16 + (lane >> 4) * 4 + r;
            if (t0 + row < n_e) {
                int slot = eoff[e] + t0 + row;
                int tok = tok_id[slot];
                float tw = tok_w[slot];
                #pragma unroll
                for (int j = 0; j < 4; j++) {
                    int col = n0 + wc * 64 + j * 16 + (lane & 15);
                    atomicAdd(&out[(size_t)tok * HDIM + col], tw * acc[i][j][r]);
                }
            }
        }
    }
}

extern "C" void kernel_launch(void* const* d_in, const int* in_sizes, int n_in,
                              void* d_out, int out_size, void* d_ws, size_t ws_size,
                              hipStream_t stream) {
    const float* x = (const float*)d_in[0];
    const float* ln1_g = (const float*)d_in[1];
    const float* ln1_b = (const float*)d_in[2];
    const float* W_ckv = (const float*)d_in[3];
    const float* W_kv = (const float*)d_in[4];
    const float* W_cq = (const float*)d_in[5];
    const float* W_q = (const float*)d_in[6];
    const float* W_qr = (const float*)d_in[7];
    const float* W_kr = (const float*)d_in[8];
    const float* W_o = (const float*)d_in[9];
    const float* ln2_g = (const float*)d_in[10];
    const float* ln2_b = (const float*)d_in[11];
    const float* cent = (const float*)d_in[12];
    const float* rbias = (const float*)d_in[13];
    const float* Wg = (const float*)d_in[14];
    const float* Wu = (const float*)d_in[15];
    const float* Wd = (const float*)d_in[16];
    float* out = (float*)d_out;

    float* ws = (float*)d_ws;
    // ---- Region A (bf16 attention pipeline; later overwritten by MoE weight alias) ----
    __hip_bfloat16* h1_bf   = (__hip_bfloat16*)ws;                    // 4096x1024
    __hip_bfloat16* c_kv_bf = h1_bf + (size_t)ROWS * HDIM;            // 4096x256
    __hip_bfloat16* c_q_bf  = c_kv_bf + (size_t)ROWS * LDIM;
    __hip_bfloat16* k_r_bf  = c_q_bf + (size_t)ROWS * LDIM;           // 4096x64
    __hip_bfloat16* q_bf    = k_r_bf + (size_t)ROWS * RDIM;           // [bh,s,128]
    __hip_bfloat16* k_bf    = q_bf + (size_t)ROWS * 2048;
    __hip_bfloat16* v_bf    = k_bf + (size_t)ROWS * 2048;             // 4096x1024
    __hip_bfloat16* vt_bf   = v_bf + (size_t)ROWS * HDIM;             // [bh,64,s]
    __hip_bfloat16* obuf_bf = vt_bf + (size_t)ROWS * HDIM;
    __hip_bfloat16* Wckv_t  = obuf_bf + (size_t)ROWS * HDIM;          // [256][1024]
    __hip_bfloat16* Wcq_t   = Wckv_t + 1024 * 256;
    __hip_bfloat16* Wkv_t   = Wcq_t + 1024 * 256;                     // [2048][256]
    __hip_bfloat16* Wq_t    = Wkv_t + 2048 * 256;                     // [1024][256]
    __hip_bfloat16* Wqr_t   = Wq_t + 1024 * 256;
    __hip_bfloat16* Wo_t    = Wqr_t + 1024 * 256;                     // [1024][1024]
    __hip_bfloat16* Wkr_t   = Wo_t + 1024 * 1024;                     // [64][256]
    // ---- MoE alias (from ws base, written after attention phase is dead) ----
    __hip_bfloat16* Wg_t  = (__hip_bfloat16*)ws;                      // 8x2048x1024 each
    __hip_bfloat16* Wu_t  = Wg_t + (size_t)NEXP * DFF * HDIM;
    __hip_bfloat16* Wd_t  = Wu_t + (size_t)NEXP * DFF * HDIM;
    __hip_bfloat16* xf_bf = Wd_t + (size_t)NEXP * DFF * HDIM;         // 4096x1024
    float* xf = ws + ((size_t)3 * NEXP * DFF * HDIM + (size_t)ROWS * HDIM) / 2;
    __hip_bfloat16* hh = (__hip_bfloat16*)xf;                         // aliases xf (dead after routing)
    float* tail = xf + (size_t)(2 * ROWS + 128) * DFF / 2;
    float* route_w = tail;
    float* tok_w = tail + ROWS * 2;
    int* ibuf = (int*)(tok_w + ROWS * 2);
    int* route_i = ibuf;           // 8192
    int* counts = ibuf + 8192;     // 8
    int* eoff = ibuf + 8200;       // 9
    int* pos = ibuf + 8212;        // 8
    int* tok_id = ibuf + 8224;     // 8192

    // 1. LN1 -> bf16
    ln_kernel<<<ROWS, 256, 0, stream>>>(x, ln1_g, ln1_b, nullptr, h1_bf);
    // 2. small weight transposes (bf16 [N][K]); 0.125 attn scale folded into W_q/W_qr
    transpose_bf16_kernel<<<dim3(4, 16, 1), 256, 0, stream>>>(W_ckv, Wckv_t, 1024, 256, 1.f);
    transpose_bf16_kernel<<<dim3(4, 16, 1), 256, 0, stream>>>(W_cq, Wcq_t, 1024, 256, 1.f);
    transpose_bf16_kernel<<<dim3(32, 4, 1), 256, 0, stream>>>(W_kv, Wkv_t, 256, 2048, 1.f);
    transpose_bf16_kernel<<<dim3(16, 4, 1), 256, 0, stream>>>(W_q, Wq_t, 256, 1024, 0.125f);
    transpose_bf16_kernel<<<dim3(16, 4, 1), 256, 0, stream>>>(W_qr, Wqr_t, 256, 1024, 0.125f);
    transpose_bf16_kernel<<<dim3(16, 16, 1), 256, 0, stream>>>(W_o, Wo_t, 1024, 1024, 1.f);
    transpose_bf16_kernel<<<dim3(1, 4, 1), 256, 0, stream>>>(W_kr, Wkr_t, 256, 64, 1.f);
    // 3-8. projections (bf16 MFMA)
    gemm_bf16_kernel<<<dim3(2, 32), 256, 0, stream>>>(h1_bf, Wckv_t, nullptr, c_kv_bf, nullptr, ROWS, 256, 1024, 0);
    gemm_bf16_kernel<<<dim3(2, 32), 256, 0, stream>>>(h1_bf, Wcq_t, nullptr, c_q_bf, nullptr, ROWS, 256, 1024, 0);
    gemm_bf16_kernel<<<dim3(8, 32), 256, 0, stream>>>(c_kv_bf, Wkv_t, nullptr, k_bf, nullptr, ROWS, 1024, 256, 1);            // k_c packed
    gemm_bf16_kernel<<<dim3(8, 32), 256, 0, stream>>>(c_kv_bf, Wkv_t + 1024 * 256, nullptr, v_bf, nullptr, ROWS, 1024, 256, 0); // v row-major
    gemm_bf16_kernel<<<dim3(8, 32), 256, 0, stream>>>(c_q_bf, Wq_t, nullptr, q_bf, nullptr, ROWS, 1024, 256, 1);              // q_c packed (scaled)
    gemm_bf16_kernel<<<dim3(8, 32), 256, 0, stream>>>(c_q_bf, Wqr_t, nullptr, q_bf, nullptr, ROWS, 1024, 256, 2);             // q_r packed HI (scaled)
    gemm_kr_kernel<<<64, 256, 0, stream>>>(c_kv_bf, Wkr_t, k_r_bf);
    // 9. RoPE + packing
    rope_q_kernel<<<(4 * 16 * 1024 * 32) / 256, 256, 0, stream>>>(q_bf);
    rope_pack_kr_kernel<<<(ROWS * 32) / 256, 256, 0, stream>>>(k_r_bf, k_bf);
    pack_vt_kernel<<<dim3(16, 16, 4), 256, 0, stream>>>(v_bf, vt_bf);
    // 10. MFMA flash attention
    attn_mfma_kernel<<<dim3(SEQ / 64, NHEAD, 4), 256, 0, stream>>>(q_bf, k_bf, vt_bf, obuf_bf);
    // 11. out = obuf @ W_o + x
    gemm_bf16_kernel<<<dim3(8, 32), 256, 0, stream>>>(obuf_bf, Wo_t, out, nullptr, x, ROWS, 1024, 1024, 0);
    // 12. LN2 -> xf (fp32) + xf_bf (bf16) fused
    ln_kernel<<<ROWS, 256, 0, stream>>>(out, ln2_g, ln2_b, xf, xf_bf);
    // 13. MoE weight transposes (overwrite region A)
    transpose_bf16_kernel<<<dim3(32, 16, NEXP), 256, 0, stream>>>(Wg, Wg_t, HDIM, DFF, 1.f);
    transpose_bf16_kernel<<<dim3(32, 16, NEXP), 256, 0, stream>>>(Wu, Wu_t, HDIM, DFF, 1.f);
    transpose_bf16_kernel<<<dim3(16, 32, NEXP), 256, 0, stream>>>(Wd, Wd_t, DFF, HDIM, 1.f);
    // 14. routing (reads fp32 xf; hh overwrites xf only afterwards)
    init_kernel<<<1, 64, 0, stream>>>(counts, pos);
    route_kernel<<<ROWS, 64, 0, stream>>>(xf, cent, rbias, route_i, route_w, counts);
    offsets_kernel<<<1, 1, 0, stream>>>(counts, eoff, out + (size_t)ROWS * HDIM);
    scatter_kernel<<<ROWS / 256, 256, 0, stream>>>(route_i, route_w, eoff, pos, tok_id, tok_w);
    // 15. MoE
    moe_gu_mfma<<<dim3(DFF / 64, 32, NEXP), 256, 0, stream>>>(xf_bf, Wg_t, Wu_t, counts, eoff, tok_id, hh);
    moe_down_mfma<<<dim3(HDIM / 128, 32, NEXP), 256, 0, stream>>>(hh, Wd_t, counts, eoff, tok_id, tok_w, out);
}